// Round 4
// baseline (1709.340 us; speedup 1.0000x reference)
//
#include <hip/hip_runtime.h>

#define NND 10000
#define EE  60000
#define DD  3000
#define HH  512
#define LL  128
#define PP  256
#define NM  3000

// All scratch lives in module BSS -> no dependency on harness ws_size.
__device__ __align__(256) char g_ws[(size_t)104 << 20];

// ---------------- init / graph build ----------------

__global__ void init_k(int* degi, int* cursor, int* flag, float* scal,
                       float* ptW, float* ntW){
    int i = blockIdx.x*256 + threadIdx.x;
    if (i < NND){ degi[i]=0; cursor[i]=0; flag[i]=0; }
    if (i < 16) scal[i]=0.f;
    if (i < HH){ ptW[i]=0.f; ntW[i]=0.f; }
}

__global__ void count_k(const int* __restrict__ ei, int* degi){
    int i = blockIdx.x*256 + threadIdx.x;
    if (i < EE) atomicAdd(&degi[ei[EE + i]], 1);
}

__global__ void dinv_k(const int* degi, float* dinv){
    int i = blockIdx.x*256 + threadIdx.x;
    if (i < NND){ float d = (float)(degi[i] + 1); dinv[i] = 1.f/sqrtf(d); }
}

__global__ void flag_k(const int* __restrict__ perm, const int* __restrict__ shuf,
                       int* flag, int* negsrc){
    int i = blockIdx.x*256 + threadIdx.x;
    if (i < NND){
        int p = perm[i];
        if (i < NM){ flag[p] = 1; negsrc[p] = -1; }
        else       { negsrc[p] = perm[NM + shuf[i - NM]]; }
    }
}

__global__ void scan_k(const int* __restrict__ degi, int* __restrict__ rowstart){
    __shared__ int sb[1024];
    __shared__ int running;
    int t = threadIdx.x;
    if (t == 0) running = 0;
    __syncthreads();
    for (int base = 0; base < NND; base += 1024){
        int v = (base + t < NND) ? degi[base + t] : 0;
        sb[t] = v;
        __syncthreads();
        for (int off = 1; off < 1024; off <<= 1){
            int x = 0;
            if (t >= off) x = sb[t - off];
            __syncthreads();
            sb[t] += x;
            __syncthreads();
        }
        int incl = sb[t];
        int total = sb[1023];
        int rbase = running;
        if (base + t < NND) rowstart[base + t] = rbase + incl - v;
        __syncthreads();
        if (t == 0) running += total;
        __syncthreads();
    }
    if (t == 0) rowstart[NND] = running;
}

__global__ void fill_k(const int* __restrict__ ei, const int* __restrict__ rowstart,
                       int* cursor, int* adj){
    int i = blockIdx.x*256 + threadIdx.x;
    if (i < EE){
        int d = ei[EE + i];
        int s = ei[i];
        int p = atomicAdd(&cursor[d], 1);
        adj[rowstart[d] + p] = s;
    }
}

// token @ W1 partial sums
__global__ __launch_bounds__(512) void tok_k(const float* __restrict__ posT,
        const float* __restrict__ negT,
        const float* __restrict__ sW1, const float* __restrict__ tW1,
        float* ptW, float* ntW){
    int b = blockIdx.x; int chunk = blockIdx.y; int j = threadIdx.x;
    const float* tok = b ? negT : posT;
    const float* Wm  = b ? tW1  : sW1;
    float acc = 0.f;
    int d0 = chunk * (DD/8), d1 = d0 + (DD/8);
    for (int d = d0; d < d1; ++d) acc += tok[d] * Wm[(long)d*HH + j];
    atomicAdd(&((b ? ntW : ptW)[j]), acc);
}

// ---------------- VALU GEMM (fp32): C = A @ B (natural layouts) ----------------
// A: M x K row-major; B: K x Nn row-major (Nn % 8 == 0, K % 8 == 0)
// C: writes cols [0,Nn) at row stride Cstride (C may be pre-offset by caller).
// epi: 0 none, 1 +bias, 2 +bias then prelu(alpha)
__global__ __launch_bounds__(256) void gemm_nn(
    const float* __restrict__ A,
    const float* __restrict__ B,
    float* __restrict__ C,
    int M, int Nn, int K, int Cstride,
    const float* __restrict__ bias,
    const float* __restrict__ alpha,
    int epi)
{
    __shared__ __align__(16) float As[64*36];   // 64 rows x 32 k (pad->36)
    __shared__ __align__(16) float Bs[32*68];   // 32 k x 64 n (pad->68)
    const int m0 = blockIdx.y*64, n0 = blockIdx.x*64;
    const int t = threadIdx.x;
    const int lrow = t >> 2,  lk  = (t & 3) * 8;   // A staging: 64 rows x 4 segs of 8
    const int lrowB = t >> 3, lkB = (t & 7) * 8;   // B staging: 32 rows x 8 segs of 8
    const int tx = t & 15, ty = t >> 4;            // 16x16 threads, 4x4 micro-tile

    float acc[4][4];
    #pragma unroll
    for (int i = 0; i < 4; i++)
        #pragma unroll
        for (int j = 0; j < 4; j++) acc[i][j] = 0.f;

    const bool arv = (m0 + lrow) < M;
    const long abase = (long)(m0 + lrow) * K;

    for (int k0 = 0; k0 < K; k0 += 32){
        float4 av0 = {0.f,0.f,0.f,0.f}, av1 = {0.f,0.f,0.f,0.f};
        float4 bv0 = {0.f,0.f,0.f,0.f}, bv1 = {0.f,0.f,0.f,0.f};
        int gk = k0 + lk;
        if (arv && gk < K){
            av0 = *(const float4*)(A + abase + gk);
            av1 = *(const float4*)(A + abase + gk + 4);
        }
        int bk = k0 + lrowB;
        if (bk < K && (n0 + lkB) < Nn){
            bv0 = *(const float4*)(B + (long)bk*Nn + n0 + lkB);
            bv1 = *(const float4*)(B + (long)bk*Nn + n0 + lkB + 4);
        }
        *(float4*)(&As[lrow*36 + lk])     = av0;
        *(float4*)(&As[lrow*36 + lk + 4]) = av1;
        *(float4*)(&Bs[lrowB*68 + lkB])     = bv0;
        *(float4*)(&Bs[lrowB*68 + lkB + 4]) = bv1;
        __syncthreads();
        #pragma unroll 8
        for (int kk = 0; kk < 32; ++kk){
            float a0 = As[(ty*4+0)*36 + kk];
            float a1 = As[(ty*4+1)*36 + kk];
            float a2 = As[(ty*4+2)*36 + kk];
            float a3 = As[(ty*4+3)*36 + kk];
            float b0 = Bs[kk*68 + tx*4 + 0];
            float b1 = Bs[kk*68 + tx*4 + 1];
            float b2 = Bs[kk*68 + tx*4 + 2];
            float b3 = Bs[kk*68 + tx*4 + 3];
            acc[0][0] += a0*b0; acc[0][1] += a0*b1; acc[0][2] += a0*b2; acc[0][3] += a0*b3;
            acc[1][0] += a1*b0; acc[1][1] += a1*b1; acc[1][2] += a1*b2; acc[1][3] += a1*b3;
            acc[2][0] += a2*b0; acc[2][1] += a2*b1; acc[2][2] += a2*b2; acc[2][3] += a2*b3;
            acc[3][0] += a3*b0; acc[3][1] += a3*b1; acc[3][2] += a3*b2; acc[3][3] += a3*b3;
        }
        __syncthreads();
    }

    float aval = (epi == 2) ? alpha[0] : 0.f;
    #pragma unroll
    for (int j = 0; j < 4; j++){
        int col = n0 + tx*4 + j;
        if (col >= Nn) continue;
        float bvv = epi ? bias[col] : 0.f;
        #pragma unroll
        for (int i = 0; i < 4; i++){
            int row = m0 + ty*4 + i;
            if (row < M){
                float v = acc[i][j] + bvv;
                if (epi == 2 && v < 0.f) v *= aval;
                C[(long)row*Cstride + col] = v;
            }
        }
    }
}

// ---------------- GCN aggregations ----------------

__global__ __launch_bounds__(256) void agg_pos_k(const float* __restrict__ XW,
    const float* __restrict__ ptW, const int* __restrict__ flag,
    const float* __restrict__ dinv, const int* __restrict__ rowstart,
    const int* __restrict__ adj, const float* __restrict__ b1,
    const float* __restrict__ a1, float* __restrict__ H1)
{
    int i = blockIdx.x; int t = threadIdx.x;
    float di = dinv[i];
    int rs = rowstart[i], re = rowstart[i+1];
    int c0 = t, c1 = t + 256;
    float p0 = ptW[c0], p1 = ptW[c1];
    float fi = flag[i] ? 1.f : 0.f;
    float acc0 = (XW[(long)i*1024 + c0] + fi*p0) * di;
    float acc1 = (XW[(long)i*1024 + c1] + fi*p1) * di;
    for (int e = rs; e < re; ++e){
        int s = adj[e]; float ds = dinv[s];
        float fs = flag[s] ? 1.f : 0.f;
        acc0 += (XW[(long)s*1024 + c0] + fs*p0) * ds;
        acc1 += (XW[(long)s*1024 + c1] + fs*p1) * ds;
    }
    float a = a1[0];
    float v0 = di*acc0 + b1[c0]; if (v0 < 0.f) v0 *= a;
    float v1 = di*acc1 + b1[c1]; if (v1 < 0.f) v1 *= a;
    H1[(long)i*512 + c0] = v0;
    H1[(long)i*512 + c1] = v1;
}

__global__ __launch_bounds__(256) void agg_neg_k(const float* __restrict__ XW,
    const float* __restrict__ ntW, const int* __restrict__ flag,
    const int* __restrict__ negsrc, const float* __restrict__ dinv,
    const int* __restrict__ rowstart, const int* __restrict__ adj,
    const float* __restrict__ b1, const float* __restrict__ a1,
    float* __restrict__ H1)
{
    int i = blockIdx.x; int t = threadIdx.x;
    float di = dinv[i];
    int rs = rowstart[i], re = rowstart[i+1];
    int c0 = t, c1 = t + 256;
    float n0v = ntW[c0], n1v = ntW[c1];
    int nsi = negsrc[i]; if (nsi < 0) nsi = 0;
    float m0 = flag[i] ? n0v : XW[(long)nsi*1024 + 512 + c0];
    float m1 = flag[i] ? n1v : XW[(long)nsi*1024 + 512 + c1];
    float acc0 = m0 * di, acc1 = m1 * di;
    for (int e = rs; e < re; ++e){
        int s = adj[e]; float ds = dinv[s];
        int fs = flag[s];
        int ns = negsrc[s]; if (ns < 0) ns = 0;
        float w0 = fs ? n0v : XW[(long)ns*1024 + 512 + c0];
        float w1 = fs ? n1v : XW[(long)ns*1024 + 512 + c1];
        acc0 += w0 * ds;
        acc1 += w1 * ds;
    }
    float a = a1[0];
    float v0 = di*acc0 + b1[c0]; if (v0 < 0.f) v0 *= a;
    float v1 = di*acc1 + b1[c1]; if (v1 < 0.f) v1 *= a;
    H1[(long)i*512 + c0] = v0;
    H1[(long)i*512 + c1] = v1;
}

__global__ __launch_bounds__(128) void agg128_k(const float* __restrict__ In,
    const float* __restrict__ dinv, const int* __restrict__ rowstart,
    const int* __restrict__ adj, const float* __restrict__ b2,
    const float* __restrict__ a2, float* __restrict__ Out)
{
    int i = blockIdx.x, t = threadIdx.x;
    float di = dinv[i];
    int rs = rowstart[i], re = rowstart[i+1];
    float acc = In[(long)i*128 + t] * di;
    for (int e = rs; e < re; ++e){
        int s = adj[e];
        acc += In[(long)s*128 + t] * dinv[s];
    }
    float v = di*acc + b2[t];
    float a = a2[0]; if (v < 0.f) v *= a;
    Out[(long)i*128 + t] = v;
}

__global__ __launch_bounds__(128) void aggrec_k(const float* __restrict__ recPre,
    const float* __restrict__ dinv, const int* __restrict__ rowstart,
    const int* __restrict__ adj, const int* __restrict__ flag,
    const int* __restrict__ perm, float* __restrict__ recAgg)
{
    int b = blockIdx.x, t = threadIdx.x;
    int i = perm[b];
    float di = dinv[i];
    int rs = rowstart[i], re = rowstart[i+1];
    float acc = 0.f; // self loop: i is a mask node -> rec row zeroed
    for (int e = rs; e < re; ++e){
        int s = adj[e];
        if (!flag[s]) acc += recPre[(long)s*128 + t] * dinv[s];
    }
    recAgg[(long)b*128 + t] = di * acc;
}

__global__ __launch_bounds__(128) void gather_k(const float* __restrict__ repP,
    const float* __restrict__ repN, const int* __restrict__ perm,
    float* __restrict__ mP, float* __restrict__ mN){
    int b = blockIdx.x, t = threadIdx.x;
    int i = perm[b];
    mP[(long)b*128 + t] = repP[(long)i*128 + t];
    mN[(long)b*128 + t] = repN[(long)i*128 + t];
}

// ---------------- DGI head ----------------

__global__ void mean_k(const float* __restrict__ posZ, float* svec){
    __shared__ float red[8][128];
    int j = threadIdx.x, g = threadIdx.y; // (128,8)
    float s = 0.f;
    for (int i = g; i < NM; i += 8) s += posZ[(long)i*128 + j];
    red[g][j] = s;
    __syncthreads();
    if (g == 0){
        float tot = 0.f;
        #pragma unroll
        for (int k = 0; k < 8; k++) tot += red[k][j];
        tot /= (float)NM;
        svec[j] = 1.f/(1.f + expf(-tot));
    }
}

__global__ void ws_k(const float* __restrict__ dgiW, const float* __restrict__ svec,
                     float* wsv){
    int i = threadIdx.x; // 128
    float a = 0.f;
    for (int j = 0; j < 128; ++j) a += dgiW[i*128 + j] * svec[j];
    wsv[i] = a;
}

__global__ __launch_bounds__(256) void dgi_k(const float* __restrict__ posZ,
    const float* __restrict__ negZ, const float* __restrict__ wsv, float* scal){
    int row = blockIdx.x*4 + (threadIdx.x >> 6);
    int lane = threadIdx.x & 63;
    if (row >= 2*NM) return;
    const float* Z = (row < NM) ? posZ : negZ;
    int r = (row < NM) ? row : row - NM;
    float v = Z[(long)r*128 + lane] * wsv[lane]
            + Z[(long)r*128 + 64 + lane] * wsv[64 + lane];
    for (int off = 32; off; off >>= 1) v += __shfl_down(v, off, 64);
    if (lane == 0){
        float d = 1.f/(1.f + expf(-v));
        float lg = (row < NM) ? logf(d + 1e-15f) : logf(1.f - d + 1e-15f);
        atomicAdd(&scal[(row < NM) ? 0 : 1], lg);
    }
}

// ---------------- cosine feature loss ----------------

__global__ __launch_bounds__(256) void cos_k(const float* __restrict__ x,
    const float* __restrict__ recMask, const int* __restrict__ perm, float* scal){
    int b = blockIdx.x, t = threadIdx.x;
    long xi = (long)perm[b]*DD;
    long ri = (long)b*DD;
    float dot = 0.f, nx = 0.f, nr = 0.f;
    for (int d = t; d < DD; d += 256){
        float xv = x[xi + d], rv = recMask[ri + d];
        dot += xv*rv; nx += xv*xv; nr += rv*rv;
    }
    for (int off = 32; off; off >>= 1){
        dot += __shfl_down(dot, off, 64);
        nx  += __shfl_down(nx,  off, 64);
        nr  += __shfl_down(nr,  off, 64);
    }
    __shared__ float sd[4], sx[4], sr[4];
    int w = t >> 6, lane = t & 63;
    if (lane == 0){ sd[w] = dot; sx[w] = nx; sr[w] = nr; }
    __syncthreads();
    if (t == 0){
        float Dv = sd[0]+sd[1]+sd[2]+sd[3];
        float Xv = sx[0]+sx[1]+sx[2]+sx[3];
        float Rv = sr[0]+sr[1]+sr[2]+sr[3];
        float c = Dv/(fmaxf(sqrtf(Xv),1e-12f)*fmaxf(sqrtf(Rv),1e-12f));
        float e = 1.f - c;
        atomicAdd(&scal[2], e*e);
    }
}

__global__ void fin_k(const float* __restrict__ scal, float* out){
    float feat = scal[2]/(float)NM;
    float dgi  = -(scal[0]/(float)NM) - (scal[1]/(float)NM);
    out[0] = feat;
    out[1] = dgi;
}

// ---------------- launch ----------------

extern "C" void kernel_launch(void* const* d_in, const int* in_sizes, int n_in,
                              void* d_out, int out_size, void* d_ws, size_t ws_size,
                              hipStream_t stream) {
    (void)in_sizes; (void)n_in; (void)out_size; (void)d_ws; (void)ws_size;
    const float* x  = (const float*)d_in[0];
    const int* ei   = (const int*)d_in[1];
    const int* perm = (const int*)d_in[2];
    const int* shuf = (const int*)d_in[3];
    const float* sW1 = (const float*)d_in[4];
    const float* sb1 = (const float*)d_in[5];
    const float* sa  = (const float*)d_in[6];
    const float* sW2 = (const float*)d_in[7];
    const float* sb2 = (const float*)d_in[8];
    const float* tW1 = (const float*)d_in[9];
    const float* tb1 = (const float*)d_in[10];
    const float* ta  = (const float*)d_in[11];
    const float* tW2 = (const float*)d_in[12];
    const float* tb2 = (const float*)d_in[13];
    const float* pW1 = (const float*)d_in[14];
    const float* pb1 = (const float*)d_in[15];
    const float* pa  = (const float*)d_in[16];
    const float* pW2 = (const float*)d_in[17];
    const float* pb2 = (const float*)d_in[18];
    const float* tpW1 = (const float*)d_in[19];
    const float* tpb1 = (const float*)d_in[20];
    const float* tpa  = (const float*)d_in[21];
    const float* tpW2 = (const float*)d_in[22];
    const float* tpb2 = (const float*)d_in[23];
    const float* dgiW = (const float*)d_in[24];
    const float* posT = (const float*)d_in[25];
    const float* negT = (const float*)d_in[26];
    const float* e2dW = (const float*)d_in[27];
    const float* dW   = (const float*)d_in[28];
    const float* db   = (const float*)d_in[29];
    float* out = (float*)d_out;

    // Scratch from module BSS (capture-safe query, no stream ops).
    void* wsp = nullptr;
    hipGetSymbolAddress(&wsp, HIP_SYMBOL(g_ws));
    char* base = (char*)wsp;
    size_t off = 0;
    auto alloc = [&](size_t b){ size_t o = off; off = (off + b + 255) & ~(size_t)255; return o; };

    float* dinv    = (float*)(base + alloc(NND*4));
    int* degi      = (int*)  (base + alloc(NND*4));
    int* rowstart  = (int*)  (base + alloc((NND+1)*4));
    int* cursor    = (int*)  (base + alloc(NND*4));
    int* adj       = (int*)  (base + alloc(EE*4));
    int* flag      = (int*)  (base + alloc(NND*4));
    int* negsrc    = (int*)  (base + alloc(NND*4));
    float* ptW     = (float*)(base + alloc(HH*4));
    float* ntW     = (float*)(base + alloc(HH*4));
    float* svec    = (float*)(base + alloc(128*4));
    float* wsv     = (float*)(base + alloc(128*4));
    float* scal    = (float*)(base + alloc(16*4));

    // region A: XW (N x 1024 f32) -> {M2p, M2n} -> recPre -> recMask
    size_t offA = alloc((size_t)NND*1024*4);
    float* XW      = (float*)(base + offA);
    float* M2p     = (float*)(base + offA);
    float* M2n     = (float*)(base + offA + (size_t)NND*128*4);
    float* recPre  = (float*)(base + offA);
    float* recMask = (float*)(base + offA);
    // region B: H1p,H1n -> {mP, mN, posH, negH, posZ, negZ}
    size_t offB = alloc((size_t)NND*512*4*2);
    float* H1p  = (float*)(base + offB);
    float* H1n  = (float*)(base + offB + (size_t)NND*512*4);
    float* mP   = (float*)(base + offB);
    float* mN   = (float*)(base + offB + (size_t)NM*128*4);
    float* posH = (float*)(base + offB + (size_t)2*NM*128*4);
    float* negH = (float*)(base + offB + (size_t)2*NM*128*4 + (size_t)NM*256*4);
    float* posZ = (float*)(base + offB + (size_t)2*NM*128*4 + (size_t)2*NM*256*4);
    float* negZ = (float*)(base + offB + (size_t)3*NM*128*4 + (size_t)2*NM*256*4);
    // region C
    float* repP   = (float*)(base + alloc((size_t)NND*128*4));
    float* repN   = (float*)(base + alloc((size_t)NND*128*4));
    float* recAgg = (float*)(base + alloc((size_t)NM*128*4));

    // ---- graph build ----
    init_k<<<(NND+255)/256, 256, 0, stream>>>(degi, cursor, flag, scal, ptW, ntW);
    count_k<<<(EE+255)/256, 256, 0, stream>>>(ei, degi);
    dinv_k<<<(NND+255)/256, 256, 0, stream>>>(degi, dinv);
    flag_k<<<(NND+255)/256, 256, 0, stream>>>(perm, shuf, flag, negsrc);
    scan_k<<<1, 1024, 0, stream>>>(degi, rowstart);
    fill_k<<<(EE+255)/256, 256, 0, stream>>>(ei, rowstart, cursor, adj);
    tok_k<<<dim3(2,8), 512, 0, stream>>>(posT, negT, sW1, tW1, ptW, ntW);

    // ---- encoder layer 1: XW[:,0:512] = x @ sW1 ; XW[:,512:1024] = x @ tW1 ----
    gemm_nn<<<dim3(8,157), 256, 0, stream>>>(x, sW1, XW,       NND, HH, DD, 1024,
                                             nullptr, nullptr, 0);
    gemm_nn<<<dim3(8,157), 256, 0, stream>>>(x, tW1, XW + 512, NND, HH, DD, 1024,
                                             nullptr, nullptr, 0);
    agg_pos_k<<<NND, 256, 0, stream>>>(XW, ptW, flag, dinv, rowstart, adj, sb1, sa, H1p);
    agg_neg_k<<<NND, 256, 0, stream>>>(XW, ntW, flag, negsrc, dinv, rowstart, adj, tb1, ta, H1n);

    // ---- encoder layer 2 ----
    gemm_nn<<<dim3(2,157), 256, 0, stream>>>(H1p, sW2, M2p, NND, LL, HH, LL,
                                             nullptr, nullptr, 0);
    gemm_nn<<<dim3(2,157), 256, 0, stream>>>(H1n, tW2, M2n, NND, LL, HH, LL,
                                             nullptr, nullptr, 0);
    agg128_k<<<NND, 128, 0, stream>>>(M2p, dinv, rowstart, adj, sb2, sa, repP);
    agg128_k<<<NND, 128, 0, stream>>>(M2n, dinv, rowstart, adj, tb2, ta, repN);

    // ---- projections on mask rows ----
    gather_k<<<NM, 128, 0, stream>>>(repP, repN, perm, mP, mN);
    gemm_nn<<<dim3(4,47), 256, 0, stream>>>(mP, pW1, posH, NM, PP, LL, PP, pb1, pa, 2);
    gemm_nn<<<dim3(2,47), 256, 0, stream>>>(posH, pW2, posZ, NM, LL, PP, LL, pb2, nullptr, 1);
    gemm_nn<<<dim3(4,47), 256, 0, stream>>>(mN, tpW1, negH, NM, PP, LL, PP, tpb1, tpa, 2);
    gemm_nn<<<dim3(2,47), 256, 0, stream>>>(negH, tpW2, negZ, NM, LL, PP, LL, tpb2, nullptr, 1);

    // ---- DGI loss ----
    mean_k<<<1, dim3(128,8), 0, stream>>>(posZ, svec);
    ws_k<<<1, 128, 0, stream>>>(dgiW, svec, wsv);
    dgi_k<<<(2*NM)/4, 256, 0, stream>>>(posZ, negZ, wsv, scal);

    // ---- decoder + feature loss ----
    gemm_nn<<<dim3(2,157), 256, 0, stream>>>(repP, e2dW, recPre, NND, LL, LL, LL,
                                             nullptr, nullptr, 0);
    aggrec_k<<<NM, 128, 0, stream>>>(recPre, dinv, rowstart, adj, flag, perm, recAgg);
    gemm_nn<<<dim3(47,47), 256, 0, stream>>>(recAgg, dW, recMask, NM, DD, LL, DD,
                                             db, nullptr, 1);
    cos_k<<<NM, 256, 0, stream>>>(x, recMask, perm, scal);

    fin_k<<<1, 1, 0, stream>>>(scal, out);
}

// Round 5
// 1010.567 us; speedup vs baseline: 1.6915x; 1.6915x over previous
//
#include <hip/hip_runtime.h>

#define NND 10000
#define EE  60000
#define DD  3000
#define HH  512
#define LL  128
#define PP  256
#define NM  3000

typedef short bf16x8 __attribute__((ext_vector_type(8)));
typedef float f32x4 __attribute__((ext_vector_type(4)));

// All scratch lives in module BSS -> no dependency on harness ws_size.
__device__ __align__(256) char g_ws[(size_t)176 << 20];

__device__ __forceinline__ unsigned short f2b(float f){
    unsigned int x = __float_as_uint(f);
    unsigned int r = x + 0x7FFFu + ((x >> 16) & 1u);
    return (unsigned short)(r >> 16);
}

// ---------------- init / graph build ----------------

__global__ void init_k(int* degi, int* cursor, int* flag, float* scal,
                       float* ptW, float* ntW){
    int i = blockIdx.x*256 + threadIdx.x;
    if (i < NND){ degi[i]=0; cursor[i]=0; flag[i]=0; }
    if (i < 16) scal[i]=0.f;
    if (i < HH){ ptW[i]=0.f; ntW[i]=0.f; }
}

__global__ void count_k(const int* __restrict__ ei, int* degi){
    int i = blockIdx.x*256 + threadIdx.x;
    if (i < EE) atomicAdd(&degi[ei[EE + i]], 1);
}

__global__ void dinv_k(const int* degi, float* dinv){
    int i = blockIdx.x*256 + threadIdx.x;
    if (i < NND){ float d = (float)(degi[i] + 1); dinv[i] = 1.f/sqrtf(d); }
}

__global__ void flag_k(const int* __restrict__ perm, const int* __restrict__ shuf,
                       int* flag, int* negsrc){
    int i = blockIdx.x*256 + threadIdx.x;
    if (i < NND){
        int p = perm[i];
        if (i < NM){ flag[p] = 1; negsrc[p] = -1; }
        else       { negsrc[p] = perm[NM + shuf[i - NM]]; }
    }
}

__global__ void scan_k(const int* __restrict__ degi, int* __restrict__ rowstart){
    __shared__ int sb[1024];
    __shared__ int running;
    int t = threadIdx.x;
    if (t == 0) running = 0;
    __syncthreads();
    for (int base = 0; base < NND; base += 1024){
        int v = (base + t < NND) ? degi[base + t] : 0;
        sb[t] = v;
        __syncthreads();
        for (int off = 1; off < 1024; off <<= 1){
            int x = 0;
            if (t >= off) x = sb[t - off];
            __syncthreads();
            sb[t] += x;
            __syncthreads();
        }
        int incl = sb[t];
        int total = sb[1023];
        int rbase = running;
        if (base + t < NND) rowstart[base + t] = rbase + incl - v;
        __syncthreads();
        if (t == 0) running += total;
        __syncthreads();
    }
    if (t == 0) rowstart[NND] = running;
}

__global__ void fill_k(const int* __restrict__ ei, const int* __restrict__ rowstart,
                       int* cursor, int* adj){
    int i = blockIdx.x*256 + threadIdx.x;
    if (i < EE){
        int d = ei[EE + i];
        int s = ei[i];
        int p = atomicAdd(&cursor[d], 1);
        adj[rowstart[d] + p] = s;
    }
}

// token @ W1 partial sums
__global__ __launch_bounds__(512) void tok_k(const float* __restrict__ posT,
        const float* __restrict__ negT,
        const float* __restrict__ sW1, const float* __restrict__ tW1,
        float* ptW, float* ntW){
    int b = blockIdx.x; int chunk = blockIdx.y; int j = threadIdx.x;
    const float* tok = b ? negT : posT;
    const float* Wm  = b ? tW1  : sW1;
    float acc = 0.f;
    int d0 = chunk * (DD/8), d1 = d0 + (DD/8);
    for (int d = d0; d < d1; ++d) acc += tok[d] * Wm[(long)d*HH + j];
    atomicAdd(&((b ? ntW : ptW)[j]), acc);
}

// ---------------- casts for MFMA path ----------------

// x (f32, NND*DD) -> xb (bf16), 8 elements/thread
__global__ __launch_bounds__(256) void cast_x_k(const float* __restrict__ x,
                                                unsigned short* __restrict__ xb){
    long i = ((long)blockIdx.x*256 + threadIdx.x) * 8;
    if (i >= (long)NND*DD) return;
    float4 a = *(const float4*)(x + i);
    float4 b = *(const float4*)(x + i + 4);
    unsigned short o[8] = {f2b(a.x),f2b(a.y),f2b(a.z),f2b(a.w),
                           f2b(b.x),f2b(b.y),f2b(b.z),f2b(b.w)};
    *(uint4*)(xb + i) = *(const uint4*)o;
}

// in: R x C f32 row-major; out (pre-offset): C rows x R cols bf16, stride R
__global__ void transcast_k(const float* __restrict__ in,
                            unsigned short* __restrict__ out, int R, int C){
    __shared__ unsigned short tile[32][33];
    int rb = blockIdx.y*32, cb = blockIdx.x*32;
    int tx = threadIdx.x, ty = threadIdx.y; // (32,8)
    for (int i = ty; i < 32; i += 8){
        int r = rb + i, c = cb + tx;
        tile[i][tx] = (r < R && c < C) ? f2b(in[(long)r*C + c]) : (unsigned short)0;
    }
    __syncthreads();
    for (int i = ty; i < 32; i += 8){
        int c = cb + i, r = rb + tx;
        if (c < C && r < R) out[(long)c*R + r] = tile[tx][i];
    }
}

// ---------------- MFMA GEMM: C(f32) = A @ BT^T ----------------
// A: MxK bf16 row-major, BT: NnxK bf16 row-major, C: f32 MxNn (stride Cstride)
__global__ __launch_bounds__(256) void gemm_bt(
    const unsigned short* __restrict__ A,
    const unsigned short* __restrict__ BT,
    float* __restrict__ C,
    int M, int Nn, int K, int Cstride)
{
    __shared__ __align__(16) unsigned short As[64*40];
    __shared__ __align__(16) unsigned short Bs[64*40];
    const int m0 = blockIdx.y*64, n0 = blockIdx.x*64;
    const int t = threadIdx.x;
    const int lrow = t >> 2, lk = (t & 3) * 8;
    const int wave = t >> 6, lane = t & 63;
    const int quad = lane >> 4, l16 = lane & 15;
    f32x4 acc[4];
    #pragma unroll
    for (int i = 0; i < 4; i++)
        for (int j = 0; j < 4; j++) acc[i][j] = 0.f;

    const long arowbase = (long)(m0 + lrow) * K;
    const long browbase = (long)(n0 + lrow) * K;
    const bool arv = (m0 + lrow) < M;
    const bool brv = (n0 + lrow) < Nn;

    for (int k0 = 0; k0 < K; k0 += 32){
        int gk = k0 + lk;
        uint4 av = {0u,0u,0u,0u};
        uint4 bv = {0u,0u,0u,0u};
        if (arv && gk < K) av = *(const uint4*)(A + arowbase + gk);
        if (brv && gk < K) bv = *(const uint4*)(BT + browbase + gk);
        *(uint4*)(&As[lrow*40 + lk]) = av;
        *(uint4*)(&Bs[lrow*40 + lk]) = bv;
        __syncthreads();
        bf16x8 af = *(const bf16x8*)(&As[(wave*16 + l16)*40 + quad*8]);
        #pragma unroll
        for (int nt = 0; nt < 4; nt++){
            bf16x8 bfr = *(const bf16x8*)(&Bs[(nt*16 + l16)*40 + quad*8]);
            acc[nt] = __builtin_amdgcn_mfma_f32_16x16x32_bf16(af, bfr, acc[nt], 0, 0, 0);
        }
        __syncthreads();
    }

    const int rowb = m0 + wave*16 + quad*4;
    #pragma unroll
    for (int nt = 0; nt < 4; nt++){
        int col = n0 + nt*16 + l16;
        if (col >= Nn) continue;
        #pragma unroll
        for (int r = 0; r < 4; r++){
            int row = rowb + r;
            if (row < M) C[(long)row*Cstride + col] = acc[nt][r];
        }
    }
}

// ---------------- VALU GEMM (fp32): C = A @ B (natural layouts) ----------------
__global__ __launch_bounds__(256) void gemm_nn(
    const float* __restrict__ A,
    const float* __restrict__ B,
    float* __restrict__ C,
    int M, int Nn, int K, int Cstride,
    const float* __restrict__ bias,
    const float* __restrict__ alpha,
    int epi)
{
    __shared__ __align__(16) float As[64*36];
    __shared__ __align__(16) float Bs[32*68];
    const int m0 = blockIdx.y*64, n0 = blockIdx.x*64;
    const int t = threadIdx.x;
    const int lrow = t >> 2,  lk  = (t & 3) * 8;
    const int lrowB = t >> 3, lkB = (t & 7) * 8;
    const int tx = t & 15, ty = t >> 4;

    float acc[4][4];
    #pragma unroll
    for (int i = 0; i < 4; i++)
        #pragma unroll
        for (int j = 0; j < 4; j++) acc[i][j] = 0.f;

    const bool arv = (m0 + lrow) < M;
    const long abase = (long)(m0 + lrow) * K;

    for (int k0 = 0; k0 < K; k0 += 32){
        float4 av0 = {0.f,0.f,0.f,0.f}, av1 = {0.f,0.f,0.f,0.f};
        float4 bv0 = {0.f,0.f,0.f,0.f}, bv1 = {0.f,0.f,0.f,0.f};
        int gk = k0 + lk;
        if (arv && gk < K){
            av0 = *(const float4*)(A + abase + gk);
            av1 = *(const float4*)(A + abase + gk + 4);
        }
        int bk = k0 + lrowB;
        if (bk < K && (n0 + lkB) < Nn){
            bv0 = *(const float4*)(B + (long)bk*Nn + n0 + lkB);
            bv1 = *(const float4*)(B + (long)bk*Nn + n0 + lkB + 4);
        }
        *(float4*)(&As[lrow*36 + lk])     = av0;
        *(float4*)(&As[lrow*36 + lk + 4]) = av1;
        *(float4*)(&Bs[lrowB*68 + lkB])     = bv0;
        *(float4*)(&Bs[lrowB*68 + lkB + 4]) = bv1;
        __syncthreads();
        #pragma unroll 8
        for (int kk = 0; kk < 32; ++kk){
            float a0 = As[(ty*4+0)*36 + kk];
            float a1 = As[(ty*4+1)*36 + kk];
            float a2 = As[(ty*4+2)*36 + kk];
            float a3 = As[(ty*4+3)*36 + kk];
            float b0 = Bs[kk*68 + tx*4 + 0];
            float b1 = Bs[kk*68 + tx*4 + 1];
            float b2 = Bs[kk*68 + tx*4 + 2];
            float b3 = Bs[kk*68 + tx*4 + 3];
            acc[0][0] += a0*b0; acc[0][1] += a0*b1; acc[0][2] += a0*b2; acc[0][3] += a0*b3;
            acc[1][0] += a1*b0; acc[1][1] += a1*b1; acc[1][2] += a1*b2; acc[1][3] += a1*b3;
            acc[2][0] += a2*b0; acc[2][1] += a2*b1; acc[2][2] += a2*b2; acc[2][3] += a2*b3;
            acc[3][0] += a3*b0; acc[3][1] += a3*b1; acc[3][2] += a3*b2; acc[3][3] += a3*b3;
        }
        __syncthreads();
    }

    float aval = (epi == 2) ? alpha[0] : 0.f;
    #pragma unroll
    for (int j = 0; j < 4; j++){
        int col = n0 + tx*4 + j;
        if (col >= Nn) continue;
        float bvv = epi ? bias[col] : 0.f;
        #pragma unroll
        for (int i = 0; i < 4; i++){
            int row = m0 + ty*4 + i;
            if (row < M){
                float v = acc[i][j] + bvv;
                if (epi == 2 && v < 0.f) v *= aval;
                C[(long)row*Cstride + col] = v;
            }
        }
    }
}

// ---------------- GCN aggregations ----------------

__global__ __launch_bounds__(256) void agg_pos_k(const float* __restrict__ XW,
    const float* __restrict__ ptW, const int* __restrict__ flag,
    const float* __restrict__ dinv, const int* __restrict__ rowstart,
    const int* __restrict__ adj, const float* __restrict__ b1,
    const float* __restrict__ a1, float* __restrict__ H1)
{
    int i = blockIdx.x; int t = threadIdx.x;
    float di = dinv[i];
    int rs = rowstart[i], re = rowstart[i+1];
    int c0 = t, c1 = t + 256;
    float p0 = ptW[c0], p1 = ptW[c1];
    float fi = flag[i] ? 1.f : 0.f;
    float acc0 = (XW[(long)i*1024 + c0] + fi*p0) * di;
    float acc1 = (XW[(long)i*1024 + c1] + fi*p1) * di;
    for (int e = rs; e < re; ++e){
        int s = adj[e]; float ds = dinv[s];
        float fs = flag[s] ? 1.f : 0.f;
        acc0 += (XW[(long)s*1024 + c0] + fs*p0) * ds;
        acc1 += (XW[(long)s*1024 + c1] + fs*p1) * ds;
    }
    float a = a1[0];
    float v0 = di*acc0 + b1[c0]; if (v0 < 0.f) v0 *= a;
    float v1 = di*acc1 + b1[c1]; if (v1 < 0.f) v1 *= a;
    H1[(long)i*512 + c0] = v0;
    H1[(long)i*512 + c1] = v1;
}

__global__ __launch_bounds__(256) void agg_neg_k(const float* __restrict__ XW,
    const float* __restrict__ ntW, const int* __restrict__ flag,
    const int* __restrict__ negsrc, const float* __restrict__ dinv,
    const int* __restrict__ rowstart, const int* __restrict__ adj,
    const float* __restrict__ b1, const float* __restrict__ a1,
    float* __restrict__ H1)
{
    int i = blockIdx.x; int t = threadIdx.x;
    float di = dinv[i];
    int rs = rowstart[i], re = rowstart[i+1];
    int c0 = t, c1 = t + 256;
    float n0v = ntW[c0], n1v = ntW[c1];
    int nsi = negsrc[i]; if (nsi < 0) nsi = 0;
    float m0 = flag[i] ? n0v : XW[(long)nsi*1024 + 512 + c0];
    float m1 = flag[i] ? n1v : XW[(long)nsi*1024 + 512 + c1];
    float acc0 = m0 * di, acc1 = m1 * di;
    for (int e = rs; e < re; ++e){
        int s = adj[e]; float ds = dinv[s];
        int fs = flag[s];
        int ns = negsrc[s]; if (ns < 0) ns = 0;
        float w0 = fs ? n0v : XW[(long)ns*1024 + 512 + c0];
        float w1 = fs ? n1v : XW[(long)ns*1024 + 512 + c1];
        acc0 += w0 * ds;
        acc1 += w1 * ds;
    }
    float a = a1[0];
    float v0 = di*acc0 + b1[c0]; if (v0 < 0.f) v0 *= a;
    float v1 = di*acc1 + b1[c1]; if (v1 < 0.f) v1 *= a;
    H1[(long)i*512 + c0] = v0;
    H1[(long)i*512 + c1] = v1;
}

__global__ __launch_bounds__(128) void agg128_k(const float* __restrict__ In,
    const float* __restrict__ dinv, const int* __restrict__ rowstart,
    const int* __restrict__ adj, const float* __restrict__ b2,
    const float* __restrict__ a2, float* __restrict__ Out)
{
    int i = blockIdx.x, t = threadIdx.x;
    float di = dinv[i];
    int rs = rowstart[i], re = rowstart[i+1];
    float acc = In[(long)i*128 + t] * di;
    for (int e = rs; e < re; ++e){
        int s = adj[e];
        acc += In[(long)s*128 + t] * dinv[s];
    }
    float v = di*acc + b2[t];
    float a = a2[0]; if (v < 0.f) v *= a;
    Out[(long)i*128 + t] = v;
}

__global__ __launch_bounds__(128) void aggrec_k(const float* __restrict__ recPre,
    const float* __restrict__ dinv, const int* __restrict__ rowstart,
    const int* __restrict__ adj, const int* __restrict__ flag,
    const int* __restrict__ perm, float* __restrict__ recAgg)
{
    int b = blockIdx.x, t = threadIdx.x;
    int i = perm[b];
    float di = dinv[i];
    int rs = rowstart[i], re = rowstart[i+1];
    float acc = 0.f; // self loop: i is a mask node -> rec row zeroed
    for (int e = rs; e < re; ++e){
        int s = adj[e];
        if (!flag[s]) acc += recPre[(long)s*128 + t] * dinv[s];
    }
    recAgg[(long)b*128 + t] = di * acc;
}

__global__ __launch_bounds__(128) void gather_k(const float* __restrict__ repP,
    const float* __restrict__ repN, const int* __restrict__ perm,
    float* __restrict__ mP, float* __restrict__ mN){
    int b = blockIdx.x, t = threadIdx.x;
    int i = perm[b];
    mP[(long)b*128 + t] = repP[(long)i*128 + t];
    mN[(long)b*128 + t] = repN[(long)i*128 + t];
}

// ---------------- DGI head ----------------

__global__ void mean_k(const float* __restrict__ posZ, float* svec){
    __shared__ float red[8][128];
    int j = threadIdx.x, g = threadIdx.y; // (128,8)
    float s = 0.f;
    for (int i = g; i < NM; i += 8) s += posZ[(long)i*128 + j];
    red[g][j] = s;
    __syncthreads();
    if (g == 0){
        float tot = 0.f;
        #pragma unroll
        for (int k = 0; k < 8; k++) tot += red[k][j];
        tot /= (float)NM;
        svec[j] = 1.f/(1.f + expf(-tot));
    }
}

__global__ void ws_k(const float* __restrict__ dgiW, const float* __restrict__ svec,
                     float* wsv){
    int i = threadIdx.x; // 128
    float a = 0.f;
    for (int j = 0; j < 128; ++j) a += dgiW[i*128 + j] * svec[j];
    wsv[i] = a;
}

__global__ __launch_bounds__(256) void dgi_k(const float* __restrict__ posZ,
    const float* __restrict__ negZ, const float* __restrict__ wsv, float* scal){
    int row = blockIdx.x*4 + (threadIdx.x >> 6);
    int lane = threadIdx.x & 63;
    if (row >= 2*NM) return;
    const float* Z = (row < NM) ? posZ : negZ;
    int r = (row < NM) ? row : row - NM;
    float v = Z[(long)r*128 + lane] * wsv[lane]
            + Z[(long)r*128 + 64 + lane] * wsv[64 + lane];
    for (int off = 32; off; off >>= 1) v += __shfl_down(v, off, 64);
    if (lane == 0){
        float d = 1.f/(1.f + expf(-v));
        float lg = (row < NM) ? logf(d + 1e-15f) : logf(1.f - d + 1e-15f);
        atomicAdd(&scal[(row < NM) ? 0 : 1], lg);
    }
}

// ---------------- cosine feature loss ----------------

__global__ __launch_bounds__(256) void cos_k(const float* __restrict__ x,
    const float* __restrict__ recMask, const int* __restrict__ perm, float* scal){
    int b = blockIdx.x, t = threadIdx.x;
    long xi = (long)perm[b]*DD;
    long ri = (long)b*DD;
    float dot = 0.f, nx = 0.f, nr = 0.f;
    for (int d = t; d < DD; d += 256){
        float xv = x[xi + d], rv = recMask[ri + d];
        dot += xv*rv; nx += xv*xv; nr += rv*rv;
    }
    for (int off = 32; off; off >>= 1){
        dot += __shfl_down(dot, off, 64);
        nx  += __shfl_down(nx,  off, 64);
        nr  += __shfl_down(nr,  off, 64);
    }
    __shared__ float sd[4], sx[4], sr[4];
    int w = t >> 6, lane = t & 63;
    if (lane == 0){ sd[w] = dot; sx[w] = nx; sr[w] = nr; }
    __syncthreads();
    if (t == 0){
        float Dv = sd[0]+sd[1]+sd[2]+sd[3];
        float Xv = sx[0]+sx[1]+sx[2]+sx[3];
        float Rv = sr[0]+sr[1]+sr[2]+sr[3];
        float c = Dv/(fmaxf(sqrtf(Xv),1e-12f)*fmaxf(sqrtf(Rv),1e-12f));
        float e = 1.f - c;
        atomicAdd(&scal[2], e*e);
    }
}

__global__ void fin_k(const float* __restrict__ scal, float* out){
    float feat = scal[2]/(float)NM;
    float dgi  = -(scal[0]/(float)NM) - (scal[1]/(float)NM);
    out[0] = feat;
    out[1] = dgi;
}

// ---------------- launch ----------------

extern "C" void kernel_launch(void* const* d_in, const int* in_sizes, int n_in,
                              void* d_out, int out_size, void* d_ws, size_t ws_size,
                              hipStream_t stream) {
    (void)in_sizes; (void)n_in; (void)out_size; (void)d_ws; (void)ws_size;
    const float* x  = (const float*)d_in[0];
    const int* ei   = (const int*)d_in[1];
    const int* perm = (const int*)d_in[2];
    const int* shuf = (const int*)d_in[3];
    const float* sW1 = (const float*)d_in[4];
    const float* sb1 = (const float*)d_in[5];
    const float* sa  = (const float*)d_in[6];
    const float* sW2 = (const float*)d_in[7];
    const float* sb2 = (const float*)d_in[8];
    const float* tW1 = (const float*)d_in[9];
    const float* tb1 = (const float*)d_in[10];
    const float* ta  = (const float*)d_in[11];
    const float* tW2 = (const float*)d_in[12];
    const float* tb2 = (const float*)d_in[13];
    const float* pW1 = (const float*)d_in[14];
    const float* pb1 = (const float*)d_in[15];
    const float* pa  = (const float*)d_in[16];
    const float* pW2 = (const float*)d_in[17];
    const float* pb2 = (const float*)d_in[18];
    const float* tpW1 = (const float*)d_in[19];
    const float* tpb1 = (const float*)d_in[20];
    const float* tpa  = (const float*)d_in[21];
    const float* tpW2 = (const float*)d_in[22];
    const float* tpb2 = (const float*)d_in[23];
    const float* dgiW = (const float*)d_in[24];
    const float* posT = (const float*)d_in[25];
    const float* negT = (const float*)d_in[26];
    const float* e2dW = (const float*)d_in[27];
    const float* dW   = (const float*)d_in[28];
    const float* db   = (const float*)d_in[29];
    float* out = (float*)d_out;

    // Scratch from module BSS (capture-safe query, no stream ops).
    void* wsp = nullptr;
    hipGetSymbolAddress(&wsp, HIP_SYMBOL(g_ws));
    char* base = (char*)wsp;
    size_t off = 0;
    auto alloc = [&](size_t b){ size_t o = off; off = (off + b + 255) & ~(size_t)255; return o; };

    float* dinv    = (float*)(base + alloc(NND*4));
    int* degi      = (int*)  (base + alloc(NND*4));
    int* rowstart  = (int*)  (base + alloc((NND+1)*4));
    int* cursor    = (int*)  (base + alloc(NND*4));
    int* adj       = (int*)  (base + alloc(EE*4));
    int* flag      = (int*)  (base + alloc(NND*4));
    int* negsrc    = (int*)  (base + alloc(NND*4));
    float* ptW     = (float*)(base + alloc(HH*4));
    float* ntW     = (float*)(base + alloc(HH*4));
    float* svec    = (float*)(base + alloc(128*4));
    float* wsv     = (float*)(base + alloc(128*4));
    float* scal    = (float*)(base + alloc(16*4));

    // bf16 staging for the big GEMM
    unsigned short* xb  = (unsigned short*)(base + alloc((size_t)NND*DD*2));
    unsigned short* W1T = (unsigned short*)(base + alloc((size_t)1024*DD*2));

    // region A: XW (N x 1024 f32) -> {M2p, M2n} -> recPre -> recMask
    size_t offA = alloc((size_t)NND*1024*4);
    float* XW      = (float*)(base + offA);
    float* M2p     = (float*)(base + offA);
    float* M2n     = (float*)(base + offA + (size_t)NND*128*4);
    float* recPre  = (float*)(base + offA);
    float* recMask = (float*)(base + offA);
    // region B: H1p,H1n -> {mP, mN, posH, negH, posZ, negZ}
    size_t offB = alloc((size_t)NND*512*4*2);
    float* H1p  = (float*)(base + offB);
    float* H1n  = (float*)(base + offB + (size_t)NND*512*4);
    float* mP   = (float*)(base + offB);
    float* mN   = (float*)(base + offB + (size_t)NM*128*4);
    float* posH = (float*)(base + offB + (size_t)2*NM*128*4);
    float* negH = (float*)(base + offB + (size_t)2*NM*128*4 + (size_t)NM*256*4);
    float* posZ = (float*)(base + offB + (size_t)2*NM*128*4 + (size_t)2*NM*256*4);
    float* negZ = (float*)(base + offB + (size_t)3*NM*128*4 + (size_t)2*NM*256*4);
    // region C
    float* repP   = (float*)(base + alloc((size_t)NND*128*4));
    float* repN   = (float*)(base + alloc((size_t)NND*128*4));
    float* recAgg = (float*)(base + alloc((size_t)NM*128*4));

    // ---- graph build ----
    init_k<<<(NND+255)/256, 256, 0, stream>>>(degi, cursor, flag, scal, ptW, ntW);
    count_k<<<(EE+255)/256, 256, 0, stream>>>(ei, degi);
    dinv_k<<<(NND+255)/256, 256, 0, stream>>>(degi, dinv);
    flag_k<<<(NND+255)/256, 256, 0, stream>>>(perm, shuf, flag, negsrc);
    scan_k<<<1, 1024, 0, stream>>>(degi, rowstart);
    fill_k<<<(EE+255)/256, 256, 0, stream>>>(ei, rowstart, cursor, adj);
    tok_k<<<dim3(2,8), 512, 0, stream>>>(posT, negT, sW1, tW1, ptW, ntW);

    // ---- bf16 staging: xb = bf16(x); W1T = bf16([sW1|tW1]^T) (1024 x 3000) ----
    cast_x_k<<<(int)(((long)NND*DD/8 + 255)/256), 256, 0, stream>>>(x, xb);
    transcast_k<<<dim3(16,94), dim3(32,8), 0, stream>>>(sW1, W1T, DD, HH);
    transcast_k<<<dim3(16,94), dim3(32,8), 0, stream>>>(tW1, W1T + (size_t)HH*DD, DD, HH);

    // ---- encoder layer 1 (MFMA): XW = xb @ [sW1|tW1] ----
    gemm_bt<<<dim3(16,157), 256, 0, stream>>>(xb, W1T, XW, NND, 1024, DD, 1024);
    agg_pos_k<<<NND, 256, 0, stream>>>(XW, ptW, flag, dinv, rowstart, adj, sb1, sa, H1p);
    agg_neg_k<<<NND, 256, 0, stream>>>(XW, ntW, flag, negsrc, dinv, rowstart, adj, tb1, ta, H1n);

    // ---- encoder layer 2 (VALU fp32) ----
    gemm_nn<<<dim3(2,157), 256, 0, stream>>>(H1p, sW2, M2p, NND, LL, HH, LL,
                                             nullptr, nullptr, 0);
    gemm_nn<<<dim3(2,157), 256, 0, stream>>>(H1n, tW2, M2n, NND, LL, HH, LL,
                                             nullptr, nullptr, 0);
    agg128_k<<<NND, 128, 0, stream>>>(M2p, dinv, rowstart, adj, sb2, sa, repP);
    agg128_k<<<NND, 128, 0, stream>>>(M2n, dinv, rowstart, adj, tb2, ta, repN);

    // ---- projections on mask rows ----
    gather_k<<<NM, 128, 0, stream>>>(repP, repN, perm, mP, mN);
    gemm_nn<<<dim3(4,47), 256, 0, stream>>>(mP, pW1, posH, NM, PP, LL, PP, pb1, pa, 2);
    gemm_nn<<<dim3(2,47), 256, 0, stream>>>(posH, pW2, posZ, NM, LL, PP, LL, pb2, nullptr, 1);
    gemm_nn<<<dim3(4,47), 256, 0, stream>>>(mN, tpW1, negH, NM, PP, LL, PP, tpb1, tpa, 2);
    gemm_nn<<<dim3(2,47), 256, 0, stream>>>(negH, tpW2, negZ, NM, LL, PP, LL, tpb2, nullptr, 1);

    // ---- DGI loss ----
    mean_k<<<1, dim3(128,8), 0, stream>>>(posZ, svec);
    ws_k<<<1, 128, 0, stream>>>(dgiW, svec, wsv);
    dgi_k<<<(2*NM)/4, 256, 0, stream>>>(posZ, negZ, wsv, scal);

    // ---- decoder + feature loss ----
    gemm_nn<<<dim3(2,157), 256, 0, stream>>>(repP, e2dW, recPre, NND, LL, LL, LL,
                                             nullptr, nullptr, 0);
    aggrec_k<<<NM, 128, 0, stream>>>(recPre, dinv, rowstart, adj, flag, perm, recAgg);
    gemm_nn<<<dim3(47,47), 256, 0, stream>>>(recAgg, dW, recMask, NM, DD, LL, DD,
                                             db, nullptr, 1);
    cos_k<<<NM, 256, 0, stream>>>(x, recMask, perm, scal);

    fin_k<<<1, 1, 0, stream>>>(scal, out);
}

// Round 6
// 918.486 us; speedup vs baseline: 1.8610x; 1.1003x over previous
//
#include <hip/hip_runtime.h>

#define NND 10000
#define EE  60000
#define DD  3000
#define HH  512
#define LL  128
#define PP  256
#define NM  3000

// padded dims for the big MFMA GEMM (no tail guards in hot loop)
#define KP  3008            // 94 * 32
#define MP  10112           // 79 * 128
#define NW  1024            // [sW1|tW1] fused width, 8*128

typedef short bf16x8 __attribute__((ext_vector_type(8)));
typedef float f32x4 __attribute__((ext_vector_type(4)));

// All scratch lives in module BSS -> no dependency on harness ws_size.
__device__ __align__(256) char g_ws[(size_t)176 << 20];

__device__ __forceinline__ unsigned short f2b(float f){
    unsigned int x = __float_as_uint(f);
    unsigned int r = x + 0x7FFFu + ((x >> 16) & 1u);
    return (unsigned short)(r >> 16);
}

__device__ __forceinline__ void gl_lds16(const void* g, void* l){
    __builtin_amdgcn_global_load_lds(
        (const __attribute__((address_space(1))) unsigned int*)g,
        (__attribute__((address_space(3))) unsigned int*)l, 16, 0, 0);
}

// ---------------- init / graph build ----------------

__global__ void init_k(int* degi, int* cursor, int* flag, float* scal,
                       float* ptW, float* ntW){
    int i = blockIdx.x*256 + threadIdx.x;
    if (i < NND){ degi[i]=0; cursor[i]=0; flag[i]=0; }
    if (i < 16) scal[i]=0.f;
    if (i < HH){ ptW[i]=0.f; ntW[i]=0.f; }
}

__global__ void count_k(const int* __restrict__ ei, int* degi){
    int i = blockIdx.x*256 + threadIdx.x;
    if (i < EE) atomicAdd(&degi[ei[EE + i]], 1);
}

__global__ void dinv_k(const int* degi, float* dinv){
    int i = blockIdx.x*256 + threadIdx.x;
    if (i < NND){ float d = (float)(degi[i] + 1); dinv[i] = 1.f/sqrtf(d); }
}

__global__ void flag_k(const int* __restrict__ perm, const int* __restrict__ shuf,
                       int* flag, int* negsrc){
    int i = blockIdx.x*256 + threadIdx.x;
    if (i < NND){
        int p = perm[i];
        if (i < NM){ flag[p] = 1; negsrc[p] = -1; }
        else       { negsrc[p] = perm[NM + shuf[i - NM]]; }
    }
}

__global__ void scan_k(const int* __restrict__ degi, int* __restrict__ rowstart){
    __shared__ int sb[1024];
    __shared__ int running;
    int t = threadIdx.x;
    if (t == 0) running = 0;
    __syncthreads();
    for (int base = 0; base < NND; base += 1024){
        int v = (base + t < NND) ? degi[base + t] : 0;
        sb[t] = v;
        __syncthreads();
        for (int off = 1; off < 1024; off <<= 1){
            int x = 0;
            if (t >= off) x = sb[t - off];
            __syncthreads();
            sb[t] += x;
            __syncthreads();
        }
        int incl = sb[t];
        int total = sb[1023];
        int rbase = running;
        if (base + t < NND) rowstart[base + t] = rbase + incl - v;
        __syncthreads();
        if (t == 0) running += total;
        __syncthreads();
    }
    if (t == 0) rowstart[NND] = running;
}

__global__ void fill_k(const int* __restrict__ ei, const int* __restrict__ rowstart,
                       int* cursor, int* adj){
    int i = blockIdx.x*256 + threadIdx.x;
    if (i < EE){
        int d = ei[EE + i];
        int s = ei[i];
        int p = atomicAdd(&cursor[d], 1);
        adj[rowstart[d] + p] = s;
    }
}

// token @ W1 partial sums
__global__ __launch_bounds__(512) void tok_k(const float* __restrict__ posT,
        const float* __restrict__ negT,
        const float* __restrict__ sW1, const float* __restrict__ tW1,
        float* ptW, float* ntW){
    int b = blockIdx.x; int chunk = blockIdx.y; int j = threadIdx.x;
    const float* tok = b ? negT : posT;
    const float* Wm  = b ? tW1  : sW1;
    float acc = 0.f;
    int d0 = chunk * (DD/8), d1 = d0 + (DD/8);
    for (int d = d0; d < d1; ++d) acc += tok[d] * Wm[(long)d*HH + j];
    atomicAdd(&((b ? ntW : ptW)[j]), acc);
}

// ---------------- casts for MFMA path ----------------

// x (f32 NND x DD) -> xb (bf16 MP x KP, zero-padded)
__global__ __launch_bounds__(256) void cast_pad_x_k(const float* __restrict__ x,
                                                    unsigned short* __restrict__ xb){
    long idx = (long)blockIdx.x*256 + threadIdx.x; // one 8-col group
    if (idx >= (long)MP*(KP/8)) return;
    int row = (int)(idx / (KP/8));
    int g   = (int)(idx % (KP/8));
    unsigned short o[8] = {0,0,0,0,0,0,0,0};
    if (row < NND && g < DD/8){
        const float* src = x + (long)row*DD + g*8;
        float4 a = *(const float4*)(src);
        float4 b = *(const float4*)(src + 4);
        o[0]=f2b(a.x); o[1]=f2b(a.y); o[2]=f2b(a.z); o[3]=f2b(a.w);
        o[4]=f2b(b.x); o[5]=f2b(b.y); o[6]=f2b(b.z); o[7]=f2b(b.w);
    }
    *(uint4*)(xb + (long)row*KP + g*8) = *(const uint4*)o;
}

// in: R x C f32 row-major; out (pre-offset): C rows x KP cols bf16 (transposed, K-padded)
__global__ void transcast_k(const float* __restrict__ in,
                            unsigned short* __restrict__ out, int R, int C){
    __shared__ unsigned short tile[32][33];
    int rb = blockIdx.y*32, cb = blockIdx.x*32;
    int tx = threadIdx.x, ty = threadIdx.y; // (32,8)
    for (int i = ty; i < 32; i += 8){
        int r = rb + i, c = cb + tx;
        tile[i][tx] = (r < R && c < C) ? f2b(in[(long)r*C + c]) : (unsigned short)0;
    }
    __syncthreads();
    for (int i = ty; i < 32; i += 8){
        int c = cb + i, r = rb + tx;
        if (c < C && r < KP) out[(long)c*KP + r] = (r < R) ? tile[tx][i] : (unsigned short)0;
    }
}

// ---------------- 128x128 MFMA GEMM (m97 structure) ----------------
// A: MP x KP bf16 (zero-padded), BT: NW x KP bf16 (zero-padded), C: f32, stride Cstride.
// grid = (NW/128, MP/128), 256 threads. Only M-guard in epilogue.
__global__ __launch_bounds__(256) void gemm128(
    const unsigned short* __restrict__ A,
    const unsigned short* __restrict__ BT,
    float* __restrict__ C,
    int M, int K, int Cstride)
{
    __shared__ __align__(16) unsigned short As[128*32];
    __shared__ __align__(16) unsigned short Bs[128*32];
    const int m0 = blockIdx.y*128, n0 = blockIdx.x*128;
    const int t = threadIdx.x;
    const int wave = t >> 6, lane = t & 63;
    const int quad = lane >> 4, l16 = lane & 15;
    const int wr = wave >> 1, wc = wave & 1;   // 2x2 wave grid, each 64x64

    const int srow = wave*32 + (lane >> 2);    // staging row for this lane (issue 0)
    const int skof = (lane & 3) * 8;           // staging k offset (8 bf16 = 16 B)
    const long abase = (long)(m0 + srow)*K + skof;
    const long bbase = (long)(n0 + srow)*K + skof;
    unsigned short* asdst0 = &As[(wave*32)*32];
    unsigned short* asdst1 = &As[(wave*32+16)*32];
    unsigned short* bsdst0 = &Bs[(wave*32)*32];
    unsigned short* bsdst1 = &Bs[(wave*32+16)*32];

    f32x4 acc[4][4];
    #pragma unroll
    for (int i = 0; i < 4; i++)
        #pragma unroll
        for (int j = 0; j < 4; j++)
            #pragma unroll
            for (int r = 0; r < 4; r++) acc[i][j][r] = 0.f;

    for (int k0 = 0; k0 < K; k0 += 32){
        gl_lds16(A + abase + k0,            asdst0);
        gl_lds16(A + abase + k0 + 16L*K,    asdst1);
        gl_lds16(BT + bbase + k0,           bsdst0);
        gl_lds16(BT + bbase + k0 + 16L*K,   bsdst1);
        __syncthreads();  // drains vmcnt then barrier
        bf16x8 af[4], bfr[4];
        #pragma unroll
        for (int mi = 0; mi < 4; mi++)
            af[mi] = *(const bf16x8*)(&As[(wr*64 + mi*16 + l16)*32 + quad*8]);
        #pragma unroll
        for (int ni = 0; ni < 4; ni++)
            bfr[ni] = *(const bf16x8*)(&Bs[(wc*64 + ni*16 + l16)*32 + quad*8]);
        #pragma unroll
        for (int mi = 0; mi < 4; mi++)
            #pragma unroll
            for (int ni = 0; ni < 4; ni++)
                acc[mi][ni] = __builtin_amdgcn_mfma_f32_16x16x32_bf16(
                                  af[mi], bfr[ni], acc[mi][ni], 0, 0, 0);
        __syncthreads();
    }

    #pragma unroll
    for (int mi = 0; mi < 4; mi++){
        const int rowb = m0 + wr*64 + mi*16 + quad*4;
        #pragma unroll
        for (int ni = 0; ni < 4; ni++){
            const int col = n0 + wc*64 + ni*16 + l16;
            #pragma unroll
            for (int r = 0; r < 4; r++){
                int row = rowb + r;
                if (row < M) C[(long)row*Cstride + col] = acc[mi][ni][r];
            }
        }
    }
}

// ---------------- VALU GEMM (fp32): C = A @ B (natural layouts) ----------------
__global__ __launch_bounds__(256) void gemm_nn(
    const float* __restrict__ A,
    const float* __restrict__ B,
    float* __restrict__ C,
    int M, int Nn, int K, int Cstride,
    const float* __restrict__ bias,
    const float* __restrict__ alpha,
    int epi)
{
    __shared__ __align__(16) float As[64*36];
    __shared__ __align__(16) float Bs[32*68];
    const int m0 = blockIdx.y*64, n0 = blockIdx.x*64;
    const int t = threadIdx.x;
    const int lrow = t >> 2,  lk  = (t & 3) * 8;
    const int lrowB = t >> 3, lkB = (t & 7) * 8;
    const int tx = t & 15, ty = t >> 4;

    float acc[4][4];
    #pragma unroll
    for (int i = 0; i < 4; i++)
        #pragma unroll
        for (int j = 0; j < 4; j++) acc[i][j] = 0.f;

    const bool arv = (m0 + lrow) < M;
    const long abase = (long)(m0 + lrow) * K;

    for (int k0 = 0; k0 < K; k0 += 32){
        float4 av0 = {0.f,0.f,0.f,0.f}, av1 = {0.f,0.f,0.f,0.f};
        float4 bv0 = {0.f,0.f,0.f,0.f}, bv1 = {0.f,0.f,0.f,0.f};
        int gk = k0 + lk;
        if (arv && gk < K){
            av0 = *(const float4*)(A + abase + gk);
            av1 = *(const float4*)(A + abase + gk + 4);
        }
        int bk = k0 + lrowB;
        if (bk < K && (n0 + lkB) < Nn){
            bv0 = *(const float4*)(B + (long)bk*Nn + n0 + lkB);
            bv1 = *(const float4*)(B + (long)bk*Nn + n0 + lkB + 4);
        }
        *(float4*)(&As[lrow*36 + lk])     = av0;
        *(float4*)(&As[lrow*36 + lk + 4]) = av1;
        *(float4*)(&Bs[lrowB*68 + lkB])     = bv0;
        *(float4*)(&Bs[lrowB*68 + lkB + 4]) = bv1;
        __syncthreads();
        #pragma unroll 8
        for (int kk = 0; kk < 32; ++kk){
            float a0 = As[(ty*4+0)*36 + kk];
            float a1 = As[(ty*4+1)*36 + kk];
            float a2 = As[(ty*4+2)*36 + kk];
            float a3 = As[(ty*4+3)*36 + kk];
            float b0 = Bs[kk*68 + tx*4 + 0];
            float b1 = Bs[kk*68 + tx*4 + 1];
            float b2 = Bs[kk*68 + tx*4 + 2];
            float b3 = Bs[kk*68 + tx*4 + 3];
            acc[0][0] += a0*b0; acc[0][1] += a0*b1; acc[0][2] += a0*b2; acc[0][3] += a0*b3;
            acc[1][0] += a1*b0; acc[1][1] += a1*b1; acc[1][2] += a1*b2; acc[1][3] += a1*b3;
            acc[2][0] += a2*b0; acc[2][1] += a2*b1; acc[2][2] += a2*b2; acc[2][3] += a2*b3;
            acc[3][0] += a3*b0; acc[3][1] += a3*b1; acc[3][2] += a3*b2; acc[3][3] += a3*b3;
        }
        __syncthreads();
    }

    float aval = (epi == 2) ? alpha[0] : 0.f;
    #pragma unroll
    for (int j = 0; j < 4; j++){
        int col = n0 + tx*4 + j;
        if (col >= Nn) continue;
        float bvv = epi ? bias[col] : 0.f;
        #pragma unroll
        for (int i = 0; i < 4; i++){
            int row = m0 + ty*4 + i;
            if (row < M){
                float v = acc[i][j] + bvv;
                if (epi == 2 && v < 0.f) v *= aval;
                C[(long)row*Cstride + col] = v;
            }
        }
    }
}

// ---------------- GCN aggregations ----------------

__global__ __launch_bounds__(256) void agg_pos_k(const float* __restrict__ XW,
    const float* __restrict__ ptW, const int* __restrict__ flag,
    const float* __restrict__ dinv, const int* __restrict__ rowstart,
    const int* __restrict__ adj, const float* __restrict__ b1,
    const float* __restrict__ a1, float* __restrict__ H1)
{
    int i = blockIdx.x; int t = threadIdx.x;
    float di = dinv[i];
    int rs = rowstart[i], re = rowstart[i+1];
    int c0 = t, c1 = t + 256;
    float p0 = ptW[c0], p1 = ptW[c1];
    float fi = flag[i] ? 1.f : 0.f;
    float acc0 = (XW[(long)i*1024 + c0] + fi*p0) * di;
    float acc1 = (XW[(long)i*1024 + c1] + fi*p1) * di;
    for (int e = rs; e < re; ++e){
        int s = adj[e]; float ds = dinv[s];
        float fs = flag[s] ? 1.f : 0.f;
        acc0 += (XW[(long)s*1024 + c0] + fs*p0) * ds;
        acc1 += (XW[(long)s*1024 + c1] + fs*p1) * ds;
    }
    float a = a1[0];
    float v0 = di*acc0 + b1[c0]; if (v0 < 0.f) v0 *= a;
    float v1 = di*acc1 + b1[c1]; if (v1 < 0.f) v1 *= a;
    H1[(long)i*512 + c0] = v0;
    H1[(long)i*512 + c1] = v1;
}

__global__ __launch_bounds__(256) void agg_neg_k(const float* __restrict__ XW,
    const float* __restrict__ ntW, const int* __restrict__ flag,
    const int* __restrict__ negsrc, const float* __restrict__ dinv,
    const int* __restrict__ rowstart, const int* __restrict__ adj,
    const float* __restrict__ b1, const float* __restrict__ a1,
    float* __restrict__ H1)
{
    int i = blockIdx.x; int t = threadIdx.x;
    float di = dinv[i];
    int rs = rowstart[i], re = rowstart[i+1];
    int c0 = t, c1 = t + 256;
    float n0v = ntW[c0], n1v = ntW[c1];
    int nsi = negsrc[i]; if (nsi < 0) nsi = 0;
    float m0 = flag[i] ? n0v : XW[(long)nsi*1024 + 512 + c0];
    float m1 = flag[i] ? n1v : XW[(long)nsi*1024 + 512 + c1];
    float acc0 = m0 * di, acc1 = m1 * di;
    for (int e = rs; e < re; ++e){
        int s = adj[e]; float ds = dinv[s];
        int fs = flag[s];
        int ns = negsrc[s]; if (ns < 0) ns = 0;
        float w0 = fs ? n0v : XW[(long)ns*1024 + 512 + c0];
        float w1 = fs ? n1v : XW[(long)ns*1024 + 512 + c1];
        acc0 += w0 * ds;
        acc1 += w1 * ds;
    }
    float a = a1[0];
    float v0 = di*acc0 + b1[c0]; if (v0 < 0.f) v0 *= a;
    float v1 = di*acc1 + b1[c1]; if (v1 < 0.f) v1 *= a;
    H1[(long)i*512 + c0] = v0;
    H1[(long)i*512 + c1] = v1;
}

__global__ __launch_bounds__(128) void agg128_k(const float* __restrict__ In,
    const float* __restrict__ dinv, const int* __restrict__ rowstart,
    const int* __restrict__ adj, const float* __restrict__ b2,
    const float* __restrict__ a2, float* __restrict__ Out)
{
    int i = blockIdx.x, t = threadIdx.x;
    float di = dinv[i];
    int rs = rowstart[i], re = rowstart[i+1];
    float acc = In[(long)i*128 + t] * di;
    for (int e = rs; e < re; ++e){
        int s = adj[e];
        acc += In[(long)s*128 + t] * dinv[s];
    }
    float v = di*acc + b2[t];
    float a = a2[0]; if (v < 0.f) v *= a;
    Out[(long)i*128 + t] = v;
}

__global__ __launch_bounds__(128) void aggrec_k(const float* __restrict__ recPre,
    const float* __restrict__ dinv, const int* __restrict__ rowstart,
    const int* __restrict__ adj, const int* __restrict__ flag,
    const int* __restrict__ perm, float* __restrict__ recAgg)
{
    int b = blockIdx.x, t = threadIdx.x;
    int i = perm[b];
    float di = dinv[i];
    int rs = rowstart[i], re = rowstart[i+1];
    float acc = 0.f; // self loop: i is a mask node -> rec row zeroed
    for (int e = rs; e < re; ++e){
        int s = adj[e];
        if (!flag[s]) acc += recPre[(long)s*128 + t] * dinv[s];
    }
    recAgg[(long)b*128 + t] = di * acc;
}

__global__ __launch_bounds__(128) void gather_k(const float* __restrict__ repP,
    const float* __restrict__ repN, const int* __restrict__ perm,
    float* __restrict__ mP, float* __restrict__ mN){
    int b = blockIdx.x, t = threadIdx.x;
    int i = perm[b];
    mP[(long)b*128 + t] = repP[(long)i*128 + t];
    mN[(long)b*128 + t] = repN[(long)i*128 + t];
}

// ---------------- DGI head ----------------

__global__ void mean_k(const float* __restrict__ posZ, float* svec){
    __shared__ float red[8][128];
    int j = threadIdx.x, g = threadIdx.y; // (128,8)
    float s = 0.f;
    for (int i = g; i < NM; i += 8) s += posZ[(long)i*128 + j];
    red[g][j] = s;
    __syncthreads();
    if (g == 0){
        float tot = 0.f;
        #pragma unroll
        for (int k = 0; k < 8; k++) tot += red[k][j];
        tot /= (float)NM;
        svec[j] = 1.f/(1.f + expf(-tot));
    }
}

__global__ void ws_k(const float* __restrict__ dgiW, const float* __restrict__ svec,
                     float* wsv){
    int i = threadIdx.x; // 128
    float a = 0.f;
    for (int j = 0; j < 128; ++j) a += dgiW[i*128 + j] * svec[j];
    wsv[i] = a;
}

__global__ __launch_bounds__(256) void dgi_k(const float* __restrict__ posZ,
    const float* __restrict__ negZ, const float* __restrict__ wsv, float* scal){
    int row = blockIdx.x*4 + (threadIdx.x >> 6);
    int lane = threadIdx.x & 63;
    if (row >= 2*NM) return;
    const float* Z = (row < NM) ? posZ : negZ;
    int r = (row < NM) ? row : row - NM;
    float v = Z[(long)r*128 + lane] * wsv[lane]
            + Z[(long)r*128 + 64 + lane] * wsv[64 + lane];
    for (int off = 32; off; off >>= 1) v += __shfl_down(v, off, 64);
    if (lane == 0){
        float d = 1.f/(1.f + expf(-v));
        float lg = (row < NM) ? logf(d + 1e-15f) : logf(1.f - d + 1e-15f);
        atomicAdd(&scal[(row < NM) ? 0 : 1], lg);
    }
}

// ---------------- cosine feature loss ----------------

__global__ __launch_bounds__(256) void cos_k(const float* __restrict__ x,
    const float* __restrict__ recMask, const int* __restrict__ perm, float* scal){
    int b = blockIdx.x, t = threadIdx.x;
    long xi = (long)perm[b]*DD;
    long ri = (long)b*DD;
    float dot = 0.f, nx = 0.f, nr = 0.f;
    for (int d = t; d < DD; d += 256){
        float xv = x[xi + d], rv = recMask[ri + d];
        dot += xv*rv; nx += xv*xv; nr += rv*rv;
    }
    for (int off = 32; off; off >>= 1){
        dot += __shfl_down(dot, off, 64);
        nx  += __shfl_down(nx,  off, 64);
        nr  += __shfl_down(nr,  off, 64);
    }
    __shared__ float sd[4], sx[4], sr[4];
    int w = t >> 6, lane = t & 63;
    if (lane == 0){ sd[w] = dot; sx[w] = nx; sr[w] = nr; }
    __syncthreads();
    if (t == 0){
        float Dv = sd[0]+sd[1]+sd[2]+sd[3];
        float Xv = sx[0]+sx[1]+sx[2]+sx[3];
        float Rv = sr[0]+sr[1]+sr[2]+sr[3];
        float c = Dv/(fmaxf(sqrtf(Xv),1e-12f)*fmaxf(sqrtf(Rv),1e-12f));
        float e = 1.f - c;
        atomicAdd(&scal[2], e*e);
    }
}

__global__ void fin_k(const float* __restrict__ scal, float* out){
    float feat = scal[2]/(float)NM;
    float dgi  = -(scal[0]/(float)NM) - (scal[1]/(float)NM);
    out[0] = feat;
    out[1] = dgi;
}

// ---------------- launch ----------------

extern "C" void kernel_launch(void* const* d_in, const int* in_sizes, int n_in,
                              void* d_out, int out_size, void* d_ws, size_t ws_size,
                              hipStream_t stream) {
    (void)in_sizes; (void)n_in; (void)out_size; (void)d_ws; (void)ws_size;
    const float* x  = (const float*)d_in[0];
    const int* ei   = (const int*)d_in[1];
    const int* perm = (const int*)d_in[2];
    const int* shuf = (const int*)d_in[3];
    const float* sW1 = (const float*)d_in[4];
    const float* sb1 = (const float*)d_in[5];
    const float* sa  = (const float*)d_in[6];
    const float* sW2 = (const float*)d_in[7];
    const float* sb2 = (const float*)d_in[8];
    const float* tW1 = (const float*)d_in[9];
    const float* tb1 = (const float*)d_in[10];
    const float* ta  = (const float*)d_in[11];
    const float* tW2 = (const float*)d_in[12];
    const float* tb2 = (const float*)d_in[13];
    const float* pW1 = (const float*)d_in[14];
    const float* pb1 = (const float*)d_in[15];
    const float* pa  = (const float*)d_in[16];
    const float* pW2 = (const float*)d_in[17];
    const float* pb2 = (const float*)d_in[18];
    const float* tpW1 = (const float*)d_in[19];
    const float* tpb1 = (const float*)d_in[20];
    const float* tpa  = (const float*)d_in[21];
    const float* tpW2 = (const float*)d_in[22];
    const float* tpb2 = (const float*)d_in[23];
    const float* dgiW = (const float*)d_in[24];
    const float* posT = (const float*)d_in[25];
    const float* negT = (const float*)d_in[26];
    const float* e2dW = (const float*)d_in[27];
    const float* dW   = (const float*)d_in[28];
    const float* db   = (const float*)d_in[29];
    float* out = (float*)d_out;

    // Scratch from module BSS (capture-safe query, no stream ops).
    void* wsp = nullptr;
    hipGetSymbolAddress(&wsp, HIP_SYMBOL(g_ws));
    char* base = (char*)wsp;
    size_t off = 0;
    auto alloc = [&](size_t b){ size_t o = off; off = (off + b + 255) & ~(size_t)255; return o; };

    float* dinv    = (float*)(base + alloc(NND*4));
    int* degi      = (int*)  (base + alloc(NND*4));
    int* rowstart  = (int*)  (base + alloc((NND+1)*4));
    int* cursor    = (int*)  (base + alloc(NND*4));
    int* adj       = (int*)  (base + alloc(EE*4));
    int* flag      = (int*)  (base + alloc(NND*4));
    int* negsrc    = (int*)  (base + alloc(NND*4));
    float* ptW     = (float*)(base + alloc(HH*4));
    float* ntW     = (float*)(base + alloc(HH*4));
    float* svec    = (float*)(base + alloc(128*4));
    float* wsv     = (float*)(base + alloc(128*4));
    float* scal    = (float*)(base + alloc(16*4));

    // bf16 staging for the big GEMM (zero-padded to MP x KP / NW x KP)
    unsigned short* xb  = (unsigned short*)(base + alloc((size_t)MP*KP*2));
    unsigned short* W1T = (unsigned short*)(base + alloc((size_t)NW*KP*2));

    // region A: XW (N x 1024 f32) -> {M2p, M2n} -> recPre -> recMask
    size_t offA = alloc((size_t)NND*1024*4);
    float* XW      = (float*)(base + offA);
    float* M2p     = (float*)(base + offA);
    float* M2n     = (float*)(base + offA + (size_t)NND*128*4);
    float* recPre  = (float*)(base + offA);
    float* recMask = (float*)(base + offA);
    // region B: H1p,H1n -> {mP, mN, posH, negH, posZ, negZ}
    size_t offB = alloc((size_t)NND*512*4*2);
    float* H1p  = (float*)(base + offB);
    float* H1n  = (float*)(base + offB + (size_t)NND*512*4);
    float* mP   = (float*)(base + offB);
    float* mN   = (float*)(base + offB + (size_t)NM*128*4);
    float* posH = (float*)(base + offB + (size_t)2*NM*128*4);
    float* negH = (float*)(base + offB + (size_t)2*NM*128*4 + (size_t)NM*256*4);
    float* posZ = (float*)(base + offB + (size_t)2*NM*128*4 + (size_t)2*NM*256*4);
    float* negZ = (float*)(base + offB + (size_t)3*NM*128*4 + (size_t)2*NM*256*4);
    // region C
    float* repP   = (float*)(base + alloc((size_t)NND*128*4));
    float* repN   = (float*)(base + alloc((size_t)NND*128*4));
    float* recAgg = (float*)(base + alloc((size_t)NM*128*4));

    // ---- graph build ----
    init_k<<<(NND+255)/256, 256, 0, stream>>>(degi, cursor, flag, scal, ptW, ntW);
    count_k<<<(EE+255)/256, 256, 0, stream>>>(ei, degi);
    dinv_k<<<(NND+255)/256, 256, 0, stream>>>(degi, dinv);
    flag_k<<<(NND+255)/256, 256, 0, stream>>>(perm, shuf, flag, negsrc);
    scan_k<<<1, 1024, 0, stream>>>(degi, rowstart);
    fill_k<<<(EE+255)/256, 256, 0, stream>>>(ei, rowstart, cursor, adj);
    tok_k<<<dim3(2,8), 512, 0, stream>>>(posT, negT, sW1, tW1, ptW, ntW);

    // ---- bf16 staging: xb = bf16(x) padded; W1T = bf16([sW1|tW1]^T) padded ----
    cast_pad_x_k<<<(int)(((long)MP*(KP/8) + 255)/256), 256, 0, stream>>>(x, xb);
    transcast_k<<<dim3(16,94), dim3(32,8), 0, stream>>>(sW1, W1T, DD, HH);
    transcast_k<<<dim3(16,94), dim3(32,8), 0, stream>>>(tW1, W1T + (size_t)HH*KP, DD, HH);

    // ---- encoder layer 1 (MFMA 128x128): XW = xb @ [sW1|tW1] ----
    gemm128<<<dim3(NW/128, MP/128), 256, 0, stream>>>(xb, W1T, XW, NND, KP, 1024);
    agg_pos_k<<<NND, 256, 0, stream>>>(XW, ptW, flag, dinv, rowstart, adj, sb1, sa, H1p);
    agg_neg_k<<<NND, 256, 0, stream>>>(XW, ntW, flag, negsrc, dinv, rowstart, adj, tb1, ta, H1n);

    // ---- encoder layer 2 (VALU fp32) ----
    gemm_nn<<<dim3(2,157), 256, 0, stream>>>(H1p, sW2, M2p, NND, LL, HH, LL,
                                             nullptr, nullptr, 0);
    gemm_nn<<<dim3(2,157), 256, 0, stream>>>(H1n, tW2, M2n, NND, LL, HH, LL,
                                             nullptr, nullptr, 0);
    agg128_k<<<NND, 128, 0, stream>>>(M2p, dinv, rowstart, adj, sb2, sa, repP);
    agg128_k<<<NND, 128, 0, stream>>>(M2n, dinv, rowstart, adj, tb2, ta, repN);

    // ---- projections on mask rows ----
    gather_k<<<NM, 128, 0, stream>>>(repP, repN, perm, mP, mN);
    gemm_nn<<<dim3(4,47), 256, 0, stream>>>(mP, pW1, posH, NM, PP, LL, PP, pb1, pa, 2);
    gemm_nn<<<dim3(2,47), 256, 0, stream>>>(posH, pW2, posZ, NM, LL, PP, LL, pb2, nullptr, 1);
    gemm_nn<<<dim3(4,47), 256, 0, stream>>>(mN, tpW1, negH, NM, PP, LL, PP, tpb1, tpa, 2);
    gemm_nn<<<dim3(2,47), 256, 0, stream>>>(negH, tpW2, negZ, NM, LL, PP, LL, tpb2, nullptr, 1);

    // ---- DGI loss ----
    mean_k<<<1, dim3(128,8), 0, stream>>>(posZ, svec);
    ws_k<<<1, 128, 0, stream>>>(dgiW, svec, wsv);
    dgi_k<<<(2*NM)/4, 256, 0, stream>>>(posZ, negZ, wsv, scal);

    // ---- decoder + feature loss ----
    gemm_nn<<<dim3(2,157), 256, 0, stream>>>(repP, e2dW, recPre, NND, LL, LL, LL,
                                             nullptr, nullptr, 0);
    aggrec_k<<<NM, 128, 0, stream>>>(recPre, dinv, rowstart, adj, flag, perm, recAgg);
    gemm_nn<<<dim3(47,47), 256, 0, stream>>>(recAgg, dW, recMask, NM, DD, LL, DD,
                                             db, nullptr, 1);
    cos_k<<<NM, 256, 0, stream>>>(x, recMask, perm, scal);

    fin_k<<<1, 1, 0, stream>>>(scal, out);
}

// Round 7
// 807.942 us; speedup vs baseline: 2.1157x; 1.1368x over previous
//
#include <hip/hip_runtime.h>

#define NND 10000
#define EE  60000
#define DD  3000
#define HH  512
#define LL  128
#define PP  256
#define NM  3000

// padded dims for the big MFMA GEMM (no tail guards in hot loop)
#define KP  3008            // 94 * 32
#define MP  10112           // 79 * 128
#define NW  1024            // [sW1|tW1] fused width, 8*128

typedef short bf16x8 __attribute__((ext_vector_type(8)));
typedef float f32x4 __attribute__((ext_vector_type(4)));

// All scratch lives in module BSS -> no dependency on harness ws_size.
__device__ __align__(256) char g_ws[(size_t)176 << 20];

__device__ __forceinline__ unsigned short f2b(float f){
    unsigned int x = __float_as_uint(f);
    unsigned int r = x + 0x7FFFu + ((x >> 16) & 1u);
    return (unsigned short)(r >> 16);
}

__device__ __forceinline__ void gl_lds16(const void* g, void* l){
    __builtin_amdgcn_global_load_lds(
        (const __attribute__((address_space(1))) unsigned int*)g,
        (__attribute__((address_space(3))) unsigned int*)l, 16, 0, 0);
}

// ---------------- init / graph build ----------------

__global__ void init_k(int* degi, int* cursor, float* scal,
                       float* ptW, float* ntW, float* svecraw, int* ecnt){
    int i = blockIdx.x*256 + threadIdx.x;
    if (i < NND){ degi[i]=0; cursor[i]=0; }
    if (i < 16) scal[i]=0.f;
    if (i == 0) ecnt[0]=0;
    if (i < 128) svecraw[i]=0.f;
    if (i < HH){ ptW[i]=0.f; ntW[i]=0.f; }
}

__global__ void count_k(const int* __restrict__ ei, int* degi){
    int i = blockIdx.x*256 + threadIdx.x;
    if (i < EE) atomicAdd(&degi[ei[EE + i]], 1);
}

// full coverage: perm is a permutation, every node written exactly once
__global__ void flag_k(const int* __restrict__ perm, const int* __restrict__ shuf,
                       int* flag, int* negsrc){
    int i = blockIdx.x*256 + threadIdx.x;
    if (i < NND){
        int p = perm[i];
        if (i < NM){ flag[p] = 1; negsrc[p] = -1; }
        else       { flag[p] = 0; negsrc[p] = perm[NM + shuf[i - NM]]; }
    }
}

// dinv + CSR segment allocation (order-free; per-block scan, 1 atomic/block)
__global__ __launch_bounds__(256) void alloc_k(const int* __restrict__ degi,
                                               float* dinv, int* rowptr, int* ecnt){
    __shared__ int sb[256];
    __shared__ int bbase;
    int t = threadIdx.x;
    int i = blockIdx.x*256 + t;
    int v = (i < NND) ? degi[i] : 0;
    sb[t] = v;
    __syncthreads();
    for (int off = 1; off < 256; off <<= 1){
        int x = 0;
        if (t >= off) x = sb[t - off];
        __syncthreads();
        sb[t] += x;
        __syncthreads();
    }
    if (t == 255) bbase = atomicAdd(ecnt, sb[255]);
    __syncthreads();
    if (i < NND){
        rowptr[i] = bbase + sb[t] - v;
        dinv[i] = 1.f/sqrtf((float)(degi[i] + 1));
    }
}

__global__ void fill_k(const int* __restrict__ ei, const int* __restrict__ rowptr,
                       int* cursor, int* adj){
    int i = blockIdx.x*256 + threadIdx.x;
    if (i < EE){
        int d = ei[EE + i];
        int s = ei[i];
        int p = atomicAdd(&cursor[d], 1);
        adj[rowptr[d] + p] = s;
    }
}

// token @ W1 partial sums
__global__ __launch_bounds__(512) void tok_k(const float* __restrict__ posT,
        const float* __restrict__ negT,
        const float* __restrict__ sW1, const float* __restrict__ tW1,
        float* ptW, float* ntW){
    int b = blockIdx.x; int chunk = blockIdx.y; int j = threadIdx.x;
    const float* tok = b ? negT : posT;
    const float* Wm  = b ? tW1  : sW1;
    float acc = 0.f;
    int d0 = chunk * (DD/8), d1 = d0 + (DD/8);
    for (int d = d0; d < d1; ++d) acc += tok[d] * Wm[(long)d*HH + j];
    atomicAdd(&((b ? ntW : ptW)[j]), acc);
}

// ---------------- casts for MFMA path ----------------

__global__ __launch_bounds__(256) void cast_pad_x_k(const float* __restrict__ x,
                                                    unsigned short* __restrict__ xb){
    long idx = (long)blockIdx.x*256 + threadIdx.x;
    if (idx >= (long)MP*(KP/8)) return;
    int row = (int)(idx / (KP/8));
    int g   = (int)(idx % (KP/8));
    unsigned short o[8] = {0,0,0,0,0,0,0,0};
    if (row < NND && g < DD/8){
        const float* src = x + (long)row*DD + g*8;
        float4 a = *(const float4*)(src);
        float4 b = *(const float4*)(src + 4);
        o[0]=f2b(a.x); o[1]=f2b(a.y); o[2]=f2b(a.z); o[3]=f2b(a.w);
        o[4]=f2b(b.x); o[5]=f2b(b.y); o[6]=f2b(b.z); o[7]=f2b(b.w);
    }
    *(uint4*)(xb + (long)row*KP + g*8) = *(const uint4*)o;
}

__global__ void transcast_k(const float* __restrict__ in,
                            unsigned short* __restrict__ out, int R, int C){
    __shared__ unsigned short tile[32][33];
    int rb = blockIdx.y*32, cb = blockIdx.x*32;
    int tx = threadIdx.x, ty = threadIdx.y; // (32,8)
    for (int i = ty; i < 32; i += 8){
        int r = rb + i, c = cb + tx;
        tile[i][tx] = (r < R && c < C) ? f2b(in[(long)r*C + c]) : (unsigned short)0;
    }
    __syncthreads();
    for (int i = ty; i < 32; i += 8){
        int c = cb + i, r = rb + tx;
        if (c < C && r < KP) out[(long)c*KP + r] = (r < R) ? tile[tx][i] : (unsigned short)0;
    }
}

// ---------------- 128x128 MFMA GEMM (m97 structure) ----------------
__global__ __launch_bounds__(256) void gemm128(
    const unsigned short* __restrict__ A,
    const unsigned short* __restrict__ BT,
    float* __restrict__ C,
    int M, int K, int Cstride)
{
    __shared__ __align__(16) unsigned short As[128*32];
    __shared__ __align__(16) unsigned short Bs[128*32];
    const int m0 = blockIdx.y*128, n0 = blockIdx.x*128;
    const int t = threadIdx.x;
    const int wave = t >> 6, lane = t & 63;
    const int quad = lane >> 4, l16 = lane & 15;
    const int wr = wave >> 1, wc = wave & 1;

    const int srow = wave*32 + (lane >> 2);
    const int skof = (lane & 3) * 8;
    const long abase = (long)(m0 + srow)*K + skof;
    const long bbase = (long)(n0 + srow)*K + skof;
    unsigned short* asdst0 = &As[(wave*32)*32];
    unsigned short* asdst1 = &As[(wave*32+16)*32];
    unsigned short* bsdst0 = &Bs[(wave*32)*32];
    unsigned short* bsdst1 = &Bs[(wave*32+16)*32];

    f32x4 acc[4][4];
    #pragma unroll
    for (int i = 0; i < 4; i++)
        #pragma unroll
        for (int j = 0; j < 4; j++)
            #pragma unroll
            for (int r = 0; r < 4; r++) acc[i][j][r] = 0.f;

    for (int k0 = 0; k0 < K; k0 += 32){
        gl_lds16(A + abase + k0,            asdst0);
        gl_lds16(A + abase + k0 + 16L*K,    asdst1);
        gl_lds16(BT + bbase + k0,           bsdst0);
        gl_lds16(BT + bbase + k0 + 16L*K,   bsdst1);
        __syncthreads();
        bf16x8 af[4], bfr[4];
        #pragma unroll
        for (int mi = 0; mi < 4; mi++)
            af[mi] = *(const bf16x8*)(&As[(wr*64 + mi*16 + l16)*32 + quad*8]);
        #pragma unroll
        for (int ni = 0; ni < 4; ni++)
            bfr[ni] = *(const bf16x8*)(&Bs[(wc*64 + ni*16 + l16)*32 + quad*8]);
        #pragma unroll
        for (int mi = 0; mi < 4; mi++)
            #pragma unroll
            for (int ni = 0; ni < 4; ni++)
                acc[mi][ni] = __builtin_amdgcn_mfma_f32_16x16x32_bf16(
                                  af[mi], bfr[ni], acc[mi][ni], 0, 0, 0);
        __syncthreads();
    }

    #pragma unroll
    for (int mi = 0; mi < 4; mi++){
        const int rowb = m0 + wr*64 + mi*16 + quad*4;
        #pragma unroll
        for (int ni = 0; ni < 4; ni++){
            const int col = n0 + wc*64 + ni*16 + l16;
            #pragma unroll
            for (int r = 0; r < 4; r++){
                int row = rowb + r;
                if (row < M) C[(long)row*Cstride + col] = acc[mi][ni][r];
            }
        }
    }
}

// ---------------- VALU GEMM (fp32): C = A[ridx?] @ B ----------------
// ridx: optional A-row indirection (gathered GEMM)
__global__ __launch_bounds__(256) void gemm_nn(
    const float* __restrict__ A,
    const float* __restrict__ B,
    float* __restrict__ C,
    int M, int Nn, int K, int Cstride,
    const float* __restrict__ bias,
    const float* __restrict__ alpha,
    int epi, const int* __restrict__ ridx)
{
    __shared__ __align__(16) float As[64*36];
    __shared__ __align__(16) float Bs[32*68];
    const int m0 = blockIdx.y*64, n0 = blockIdx.x*64;
    const int t = threadIdx.x;
    const int lrow = t >> 2,  lk  = (t & 3) * 8;
    const int lrowB = t >> 3, lkB = (t & 7) * 8;
    const int tx = t & 15, ty = t >> 4;

    float acc[4][4];
    #pragma unroll
    for (int i = 0; i < 4; i++)
        #pragma unroll
        for (int j = 0; j < 4; j++) acc[i][j] = 0.f;

    const bool arv = (m0 + lrow) < M;
    long arow = 0;
    if (arv) arow = ridx ? (long)ridx[m0 + lrow] : (long)(m0 + lrow);
    const long abase = arow * K;

    for (int k0 = 0; k0 < K; k0 += 32){
        float4 av0 = {0.f,0.f,0.f,0.f}, av1 = {0.f,0.f,0.f,0.f};
        float4 bv0 = {0.f,0.f,0.f,0.f}, bv1 = {0.f,0.f,0.f,0.f};
        int gk = k0 + lk;
        if (arv && gk < K){
            av0 = *(const float4*)(A + abase + gk);
            av1 = *(const float4*)(A + abase + gk + 4);
        }
        int bk = k0 + lrowB;
        if (bk < K && (n0 + lkB) < Nn){
            bv0 = *(const float4*)(B + (long)bk*Nn + n0 + lkB);
            bv1 = *(const float4*)(B + (long)bk*Nn + n0 + lkB + 4);
        }
        *(float4*)(&As[lrow*36 + lk])     = av0;
        *(float4*)(&As[lrow*36 + lk + 4]) = av1;
        *(float4*)(&Bs[lrowB*68 + lkB])     = bv0;
        *(float4*)(&Bs[lrowB*68 + lkB + 4]) = bv1;
        __syncthreads();
        #pragma unroll 8
        for (int kk = 0; kk < 32; ++kk){
            float a0 = As[(ty*4+0)*36 + kk];
            float a1 = As[(ty*4+1)*36 + kk];
            float a2 = As[(ty*4+2)*36 + kk];
            float a3 = As[(ty*4+3)*36 + kk];
            float b0 = Bs[kk*68 + tx*4 + 0];
            float b1 = Bs[kk*68 + tx*4 + 1];
            float b2 = Bs[kk*68 + tx*4 + 2];
            float b3 = Bs[kk*68 + tx*4 + 3];
            acc[0][0] += a0*b0; acc[0][1] += a0*b1; acc[0][2] += a0*b2; acc[0][3] += a0*b3;
            acc[1][0] += a1*b0; acc[1][1] += a1*b1; acc[1][2] += a1*b2; acc[1][3] += a1*b3;
            acc[2][0] += a2*b0; acc[2][1] += a2*b1; acc[2][2] += a2*b2; acc[2][3] += a2*b3;
            acc[3][0] += a3*b0; acc[3][1] += a3*b1; acc[3][2] += a3*b2; acc[3][3] += a3*b3;
        }
        __syncthreads();
    }

    float aval = (epi == 2) ? alpha[0] : 0.f;
    #pragma unroll
    for (int j = 0; j < 4; j++){
        int col = n0 + tx*4 + j;
        if (col >= Nn) continue;
        float bvv = epi ? bias[col] : 0.f;
        #pragma unroll
        for (int i = 0; i < 4; i++){
            int row = m0 + ty*4 + i;
            if (row < M){
                float v = acc[i][j] + bvv;
                if (epi == 2 && v < 0.f) v *= aval;
                C[(long)row*Cstride + col] = v;
            }
        }
    }
}

// ---------------- fused GCN layer-1 aggregation (pos + neg) ----------------

__global__ __launch_bounds__(256) void agg1_k(const float* __restrict__ XW,
    const float* __restrict__ ptW, const float* __restrict__ ntW,
    const int* __restrict__ flag, const int* __restrict__ negsrc,
    const float* __restrict__ dinv, const int* __restrict__ rowptr,
    const int* __restrict__ degi, const int* __restrict__ adj,
    const float* __restrict__ sb1, const float* __restrict__ sav,
    const float* __restrict__ tb1, const float* __restrict__ tav,
    float* __restrict__ H1p, float* __restrict__ H1n)
{
    int i = blockIdx.x; int t = threadIdx.x;
    float di = dinv[i];
    int rs = rowptr[i], re = rs + degi[i];
    int c0 = t, c1 = t + 256;
    float p0 = ptW[c0], p1 = ptW[c1];
    float n0v = ntW[c0], n1v = ntW[c1];
    int fi = flag[i];
    int nsi = negsrc[i]; if (nsi < 0) nsi = 0;
    float ffi = fi ? 1.f : 0.f;
    float pa0 = (XW[(long)i*1024 + c0] + ffi*p0) * di;
    float pa1 = (XW[(long)i*1024 + c1] + ffi*p1) * di;
    float na0 = (fi ? n0v : XW[(long)nsi*1024 + 512 + c0]) * di;
    float na1 = (fi ? n1v : XW[(long)nsi*1024 + 512 + c1]) * di;
    for (int e = rs; e < re; ++e){
        int s = adj[e]; float ds = dinv[s];
        int fs = flag[s];
        int ns = negsrc[s]; if (ns < 0) ns = 0;
        float ffs = fs ? 1.f : 0.f;
        pa0 += (XW[(long)s*1024 + c0] + ffs*p0) * ds;
        pa1 += (XW[(long)s*1024 + c1] + ffs*p1) * ds;
        na0 += (fs ? n0v : XW[(long)ns*1024 + 512 + c0]) * ds;
        na1 += (fs ? n1v : XW[(long)ns*1024 + 512 + c1]) * ds;
    }
    float sa_ = sav[0], ta_ = tav[0];
    float v0 = di*pa0 + sb1[c0]; if (v0 < 0.f) v0 *= sa_;
    float v1 = di*pa1 + sb1[c1]; if (v1 < 0.f) v1 *= sa_;
    float w0 = di*na0 + tb1[c0]; if (w0 < 0.f) w0 *= ta_;
    float w1 = di*na1 + tb1[c1]; if (w1 < 0.f) w1 *= ta_;
    H1p[(long)i*512 + c0] = v0;
    H1p[(long)i*512 + c1] = v1;
    H1n[(long)i*512 + c0] = w0;
    H1n[(long)i*512 + c1] = w1;
}

__global__ __launch_bounds__(128) void agg128_k(const float* __restrict__ In,
    const float* __restrict__ dinv, const int* __restrict__ rowptr,
    const int* __restrict__ degi, const int* __restrict__ adj,
    const float* __restrict__ b2, const float* __restrict__ a2,
    float* __restrict__ Out)
{
    int i = blockIdx.x, t = threadIdx.x;
    float di = dinv[i];
    int rs = rowptr[i], re = rs + degi[i];
    float acc = In[(long)i*128 + t] * di;
    for (int e = rs; e < re; ++e){
        int s = adj[e];
        acc += In[(long)s*128 + t] * dinv[s];
    }
    float v = di*acc + b2[t];
    float a = a2[0]; if (v < 0.f) v *= a;
    Out[(long)i*128 + t] = v;
}

__global__ __launch_bounds__(128) void aggrec_k(const float* __restrict__ recPre,
    const float* __restrict__ dinv, const int* __restrict__ rowptr,
    const int* __restrict__ degi, const int* __restrict__ adj,
    const int* __restrict__ flag, const int* __restrict__ perm,
    float* __restrict__ recAgg)
{
    int b = blockIdx.x, t = threadIdx.x;
    int i = perm[b];
    float di = dinv[i];
    int rs = rowptr[i], re = rs + degi[i];
    float acc = 0.f; // self loop: i is a mask node -> rec row zeroed
    for (int e = rs; e < re; ++e){
        int s = adj[e];
        if (!flag[s]) acc += recPre[(long)s*128 + t] * dinv[s];
    }
    recAgg[(long)b*128 + t] = di * acc;
}

// ---------------- DGI head ----------------

// partial column sums of posZ, 64 rows per block
__global__ __launch_bounds__(128) void meanp_k(const float* __restrict__ posZ,
                                               float* svecraw){
    int j = threadIdx.x;
    int r0 = blockIdx.x*64, r1 = r0 + 64; if (r1 > NM) r1 = NM;
    float s = 0.f;
    for (int r = r0; r < r1; ++r) s += posZ[(long)r*128 + j];
    atomicAdd(&svecraw[j], s);
}

__global__ void ws_k(const float* __restrict__ dgiW, const float* __restrict__ svecraw,
                     float* wsv){
    __shared__ float s[128];
    int i = threadIdx.x; // 128
    s[i] = 1.f/(1.f + expf(-svecraw[i]/(float)NM));
    __syncthreads();
    float a = 0.f;
    for (int j = 0; j < 128; ++j) a += dgiW[i*128 + j] * s[j];
    wsv[i] = a;
}

__global__ __launch_bounds__(256) void dgi_k(const float* __restrict__ posZ,
    const float* __restrict__ negZ, const float* __restrict__ wsv, float* scal){
    int row = blockIdx.x*4 + (threadIdx.x >> 6);
    int lane = threadIdx.x & 63;
    if (row >= 2*NM) return;
    const float* Z = (row < NM) ? posZ : negZ;
    int r = (row < NM) ? row : row - NM;
    float v = Z[(long)r*128 + lane] * wsv[lane]
            + Z[(long)r*128 + 64 + lane] * wsv[64 + lane];
    for (int off = 32; off; off >>= 1) v += __shfl_down(v, off, 64);
    if (lane == 0){
        float d = 1.f/(1.f + expf(-v));
        float lg = (row < NM) ? logf(d + 1e-15f) : logf(1.f - d + 1e-15f);
        atomicAdd(&scal[(row < NM) ? 0 : 1], lg);
    }
}

// ---------------- cosine feature loss ----------------

__global__ __launch_bounds__(256) void cos_k(const float* __restrict__ x,
    const float* __restrict__ recMask, const int* __restrict__ perm, float* scal){
    int b = blockIdx.x, t = threadIdx.x;
    long xi = (long)perm[b]*DD;
    long ri = (long)b*DD;
    float dot = 0.f, nx = 0.f, nr = 0.f;
    for (int d = t; d < DD; d += 256){
        float xv = x[xi + d], rv = recMask[ri + d];
        dot += xv*rv; nx += xv*xv; nr += rv*rv;
    }
    for (int off = 32; off; off >>= 1){
        dot += __shfl_down(dot, off, 64);
        nx  += __shfl_down(nx,  off, 64);
        nr  += __shfl_down(nr,  off, 64);
    }
    __shared__ float sd[4], sx[4], sr[4];
    int w = t >> 6, lane = t & 63;
    if (lane == 0){ sd[w] = dot; sx[w] = nx; sr[w] = nr; }
    __syncthreads();
    if (t == 0){
        float Dv = sd[0]+sd[1]+sd[2]+sd[3];
        float Xv = sx[0]+sx[1]+sx[2]+sx[3];
        float Rv = sr[0]+sr[1]+sr[2]+sr[3];
        float c = Dv/(fmaxf(sqrtf(Xv),1e-12f)*fmaxf(sqrtf(Rv),1e-12f));
        float e = 1.f - c;
        atomicAdd(&scal[2], e*e);
    }
}

__global__ void fin_k(const float* __restrict__ scal, float* out){
    float feat = scal[2]/(float)NM;
    float dgi  = -(scal[0]/(float)NM) - (scal[1]/(float)NM);
    out[0] = feat;
    out[1] = dgi;
}

// ---------------- launch ----------------

extern "C" void kernel_launch(void* const* d_in, const int* in_sizes, int n_in,
                              void* d_out, int out_size, void* d_ws, size_t ws_size,
                              hipStream_t stream) {
    (void)in_sizes; (void)n_in; (void)out_size; (void)d_ws; (void)ws_size;
    const float* x  = (const float*)d_in[0];
    const int* ei   = (const int*)d_in[1];
    const int* perm = (const int*)d_in[2];
    const int* shuf = (const int*)d_in[3];
    const float* sW1 = (const float*)d_in[4];
    const float* sb1 = (const float*)d_in[5];
    const float* sa  = (const float*)d_in[6];
    const float* sW2 = (const float*)d_in[7];
    const float* sb2 = (const float*)d_in[8];
    const float* tW1 = (const float*)d_in[9];
    const float* tb1 = (const float*)d_in[10];
    const float* ta  = (const float*)d_in[11];
    const float* tW2 = (const float*)d_in[12];
    const float* tb2 = (const float*)d_in[13];
    const float* pW1 = (const float*)d_in[14];
    const float* pb1 = (const float*)d_in[15];
    const float* pa  = (const float*)d_in[16];
    const float* pW2 = (const float*)d_in[17];
    const float* pb2 = (const float*)d_in[18];
    const float* tpW1 = (const float*)d_in[19];
    const float* tpb1 = (const float*)d_in[20];
    const float* tpa  = (const float*)d_in[21];
    const float* tpW2 = (const float*)d_in[22];
    const float* tpb2 = (const float*)d_in[23];
    const float* dgiW = (const float*)d_in[24];
    const float* posT = (const float*)d_in[25];
    const float* negT = (const float*)d_in[26];
    const float* e2dW = (const float*)d_in[27];
    const float* dW   = (const float*)d_in[28];
    const float* db   = (const float*)d_in[29];
    float* out = (float*)d_out;

    void* wsp = nullptr;
    hipGetSymbolAddress(&wsp, HIP_SYMBOL(g_ws));
    char* base = (char*)wsp;
    size_t off = 0;
    auto alloc = [&](size_t b){ size_t o = off; off = (off + b + 255) & ~(size_t)255; return o; };

    float* dinv    = (float*)(base + alloc(NND*4));
    int* degi      = (int*)  (base + alloc(NND*4));
    int* rowptr    = (int*)  (base + alloc(NND*4));
    int* cursor    = (int*)  (base + alloc(NND*4));
    int* adj       = (int*)  (base + alloc(EE*4));
    int* flag      = (int*)  (base + alloc(NND*4));
    int* negsrc    = (int*)  (base + alloc(NND*4));
    int* ecnt      = (int*)  (base + alloc(16*4));
    float* ptW     = (float*)(base + alloc(HH*4));
    float* ntW     = (float*)(base + alloc(HH*4));
    float* svecraw = (float*)(base + alloc(128*4));
    float* wsv     = (float*)(base + alloc(128*4));
    float* scal    = (float*)(base + alloc(16*4));

    unsigned short* xb  = (unsigned short*)(base + alloc((size_t)MP*KP*2));
    unsigned short* W1T = (unsigned short*)(base + alloc((size_t)NW*KP*2));

    // region A: XW (N x 1024 f32) -> {M2p, M2n} -> recPre -> recMask
    size_t offA = alloc((size_t)NND*1024*4);
    float* XW      = (float*)(base + offA);
    float* M2p     = (float*)(base + offA);
    float* M2n     = (float*)(base + offA + (size_t)NND*128*4);
    float* recPre  = (float*)(base + offA);
    float* recMask = (float*)(base + offA);
    // region B: H1p,H1n -> {posH, negH, posZ, negZ}
    size_t offB = alloc((size_t)NND*512*4*2);
    float* H1p  = (float*)(base + offB);
    float* H1n  = (float*)(base + offB + (size_t)NND*512*4);
    float* posH = (float*)(base + offB + (size_t)2*NM*128*4);
    float* negH = (float*)(base + offB + (size_t)2*NM*128*4 + (size_t)NM*256*4);
    float* posZ = (float*)(base + offB + (size_t)2*NM*128*4 + (size_t)2*NM*256*4);
    float* negZ = (float*)(base + offB + (size_t)3*NM*128*4 + (size_t)2*NM*256*4);
    // region C
    float* repP   = (float*)(base + alloc((size_t)NND*128*4));
    float* repN   = (float*)(base + alloc((size_t)NND*128*4));
    float* recAgg = (float*)(base + alloc((size_t)NM*128*4));

    // ---- graph build (scan-free) ----
    init_k<<<(NND+255)/256, 256, 0, stream>>>(degi, cursor, scal, ptW, ntW, svecraw, ecnt);
    flag_k<<<(NND+255)/256, 256, 0, stream>>>(perm, shuf, flag, negsrc);
    count_k<<<(EE+255)/256, 256, 0, stream>>>(ei, degi);
    alloc_k<<<(NND+255)/256, 256, 0, stream>>>(degi, dinv, rowptr, ecnt);
    fill_k<<<(EE+255)/256, 256, 0, stream>>>(ei, rowptr, cursor, adj);
    tok_k<<<dim3(2,8), 512, 0, stream>>>(posT, negT, sW1, tW1, ptW, ntW);

    // ---- bf16 staging ----
    cast_pad_x_k<<<(int)(((long)MP*(KP/8) + 255)/256), 256, 0, stream>>>(x, xb);
    transcast_k<<<dim3(16,94), dim3(32,8), 0, stream>>>(sW1, W1T, DD, HH);
    transcast_k<<<dim3(16,94), dim3(32,8), 0, stream>>>(tW1, W1T + (size_t)HH*KP, DD, HH);

    // ---- encoder layer 1 (MFMA 128x128) + fused aggregation ----
    gemm128<<<dim3(NW/128, MP/128), 256, 0, stream>>>(xb, W1T, XW, NND, KP, 1024);
    agg1_k<<<NND, 256, 0, stream>>>(XW, ptW, ntW, flag, negsrc, dinv, rowptr, degi, adj,
                                    sb1, sa, tb1, ta, H1p, H1n);

    // ---- encoder layer 2 ----
    gemm_nn<<<dim3(2,157), 256, 0, stream>>>(H1p, sW2, M2p, NND, LL, HH, LL,
                                             nullptr, nullptr, 0, nullptr);
    gemm_nn<<<dim3(2,157), 256, 0, stream>>>(H1n, tW2, M2n, NND, LL, HH, LL,
                                             nullptr, nullptr, 0, nullptr);
    agg128_k<<<NND, 128, 0, stream>>>(M2p, dinv, rowptr, degi, adj, sb2, sa, repP);
    agg128_k<<<NND, 128, 0, stream>>>(M2n, dinv, rowptr, degi, adj, tb2, ta, repN);

    // ---- projections on mask rows (gathered A via perm) ----
    gemm_nn<<<dim3(4,47), 256, 0, stream>>>(repP, pW1, posH, NM, PP, LL, PP, pb1, pa, 2, perm);
    gemm_nn<<<dim3(2,47), 256, 0, stream>>>(posH, pW2, posZ, NM, LL, PP, LL, pb2, nullptr, 1, nullptr);
    gemm_nn<<<dim3(4,47), 256, 0, stream>>>(repN, tpW1, negH, NM, PP, LL, PP, tpb1, tpa, 2, perm);
    gemm_nn<<<dim3(2,47), 256, 0, stream>>>(negH, tpW2, negZ, NM, LL, PP, LL, tpb2, nullptr, 1, nullptr);

    // ---- DGI loss ----
    meanp_k<<<47, 128, 0, stream>>>(posZ, svecraw);
    ws_k<<<1, 128, 0, stream>>>(dgiW, svecraw, wsv);
    dgi_k<<<(2*NM)/4, 256, 0, stream>>>(posZ, negZ, wsv, scal);

    // ---- decoder + feature loss ----
    gemm_nn<<<dim3(2,157), 256, 0, stream>>>(repP, e2dW, recPre, NND, LL, LL, LL,
                                             nullptr, nullptr, 0, nullptr);
    aggrec_k<<<NM, 128, 0, stream>>>(recPre, dinv, rowptr, degi, adj, flag, perm, recAgg);
    gemm_nn<<<dim3(47,47), 256, 0, stream>>>(recAgg, dW, recMask, NM, DD, LL, DD,
                                             db, nullptr, 1, nullptr);
    cos_k<<<NM, 256, 0, stream>>>(x, recMask, perm, scal);

    fin_k<<<1, 1, 0, stream>>>(scal, out);
}

// Round 8
// 681.713 us; speedup vs baseline: 2.5074x; 1.1852x over previous
//
#include <hip/hip_runtime.h>

#define NND 10000
#define EE  60000
#define DD  3000
#define HH  512
#define LL  128
#define PP  256
#define NM  3000

// padded dims for the big MFMA GEMM (no tail guards in hot loop)
#define KP  3008            // 94 * 32
#define MP  10112           // 79 * 128
#define NW  1024            // [sW1|tW1] fused width, 8*128

typedef short bf16x8 __attribute__((ext_vector_type(8)));
typedef float f32x4 __attribute__((ext_vector_type(4)));

// All scratch lives in module BSS -> no dependency on harness ws_size.
__device__ __align__(256) char g_ws[(size_t)176 << 20];

__device__ __forceinline__ unsigned short f2b(float f){
    unsigned int x = __float_as_uint(f);
    unsigned int r = x + 0x7FFFu + ((x >> 16) & 1u);
    return (unsigned short)(r >> 16);
}
__device__ __forceinline__ float b2f(unsigned short u){
    return __uint_as_float(((unsigned int)u) << 16);
}
// uint holding 2 bf16 (low = col c, high = col c+1)
__device__ __forceinline__ float2 bpair(unsigned int u){
    float2 r;
    r.x = __uint_as_float(u << 16);
    r.y = __uint_as_float(u & 0xffff0000u);
    return r;
}
__device__ __forceinline__ unsigned int packb(float a, float b){
    return (unsigned int)f2b(a) | ((unsigned int)f2b(b) << 16);
}

__device__ __forceinline__ void gl_lds16(const void* g, void* l){
    __builtin_amdgcn_global_load_lds(
        (const __attribute__((address_space(1))) unsigned int*)g,
        (__attribute__((address_space(3))) unsigned int*)l, 16, 0, 0);
}

// ---------------- init / graph build ----------------

__global__ void init_k(int* degi, int* cursor, float* scal,
                       float* ptW, float* ntW, float* svecraw, int* ecnt){
    int i = blockIdx.x*256 + threadIdx.x;
    if (i < NND){ degi[i]=0; cursor[i]=0; }
    if (i < 16) scal[i]=0.f;
    if (i == 0) ecnt[0]=0;
    if (i < 128) svecraw[i]=0.f;
    if (i < HH){ ptW[i]=0.f; ntW[i]=0.f; }
}

__global__ void count_k(const int* __restrict__ ei, int* degi){
    int i = blockIdx.x*256 + threadIdx.x;
    if (i < EE) atomicAdd(&degi[ei[EE + i]], 1);
}

__global__ void flag_k(const int* __restrict__ perm, const int* __restrict__ shuf,
                       int* flag, int* negsrc){
    int i = blockIdx.x*256 + threadIdx.x;
    if (i < NND){
        int p = perm[i];
        if (i < NM){ flag[p] = 1; negsrc[p] = -1; }
        else       { flag[p] = 0; negsrc[p] = perm[NM + shuf[i - NM]]; }
    }
}

// dinv + CSR segment allocation (order-free; per-block scan, 1 atomic/block)
__global__ __launch_bounds__(256) void alloc_k(const int* __restrict__ degi,
                                               float* dinv, int* rowptr, int* ecnt){
    __shared__ int sb[256];
    __shared__ int bbase;
    int t = threadIdx.x;
    int i = blockIdx.x*256 + t;
    int v = (i < NND) ? degi[i] : 0;
    sb[t] = v;
    __syncthreads();
    for (int off = 1; off < 256; off <<= 1){
        int x = 0;
        if (t >= off) x = sb[t - off];
        __syncthreads();
        sb[t] += x;
        __syncthreads();
    }
    if (t == 255) bbase = atomicAdd(ecnt, sb[255]);
    __syncthreads();
    if (i < NND){
        rowptr[i] = bbase + sb[t] - v;
        dinv[i] = 1.f/sqrtf((float)(degi[i] + 1));
    }
}

__global__ void fill_k(const int* __restrict__ ei, const int* __restrict__ rowptr,
                       int* cursor, int* adj){
    int i = blockIdx.x*256 + threadIdx.x;
    if (i < EE){
        int d = ei[EE + i];
        int s = ei[i];
        int p = atomicAdd(&cursor[d], 1);
        adj[rowptr[d] + p] = s;
    }
}

// token @ W1 partial sums
__global__ __launch_bounds__(512) void tok_k(const float* __restrict__ posT,
        const float* __restrict__ negT,
        const float* __restrict__ sW1, const float* __restrict__ tW1,
        float* ptW, float* ntW){
    int b = blockIdx.x; int chunk = blockIdx.y; int j = threadIdx.x;
    const float* tok = b ? negT : posT;
    const float* Wm  = b ? tW1  : sW1;
    float acc = 0.f;
    int d0 = chunk * (DD/8), d1 = d0 + (DD/8);
    for (int d = d0; d < d1; ++d) acc += tok[d] * Wm[(long)d*HH + j];
    atomicAdd(&((b ? ntW : ptW)[j]), acc);
}

// ---------------- casts for MFMA path ----------------

__global__ __launch_bounds__(256) void cast_pad_x_k(const float* __restrict__ x,
                                                    unsigned short* __restrict__ xb){
    long idx = (long)blockIdx.x*256 + threadIdx.x;
    if (idx >= (long)MP*(KP/8)) return;
    int row = (int)(idx / (KP/8));
    int g   = (int)(idx % (KP/8));
    unsigned short o[8] = {0,0,0,0,0,0,0,0};
    if (row < NND && g < DD/8){
        const float* src = x + (long)row*DD + g*8;
        float4 a = *(const float4*)(src);
        float4 b = *(const float4*)(src + 4);
        o[0]=f2b(a.x); o[1]=f2b(a.y); o[2]=f2b(a.z); o[3]=f2b(a.w);
        o[4]=f2b(b.x); o[5]=f2b(b.y); o[6]=f2b(b.z); o[7]=f2b(b.w);
    }
    *(uint4*)(xb + (long)row*KP + g*8) = *(const uint4*)o;
}

// batched transpose-cast: out[c*OS + r] = bf16(in[r*C + c]), zero-fill r in [R,OS)
struct TBatch {
    const float* in[10];
    unsigned short* out[10];
    int R[10], C[10], OS[10];
    int t0[11];
};

__global__ void transbatch_k(TBatch tb){
    __shared__ unsigned short tile[32][33];
    int b = blockIdx.x;
    int d = 0;
    while (d < 9 && b >= tb.t0[d+1]) d++;
    const float* in = tb.in[d];
    unsigned short* out = tb.out[d];
    int R = tb.R[d], C = tb.C[d], OS = tb.OS[d];
    int lt = b - tb.t0[d];
    int Ctiles = (C + 31) >> 5;
    int rt = lt / Ctiles, ct = lt % Ctiles;
    int rb = rt*32, cb = ct*32;
    int tx = threadIdx.x, ty = threadIdx.y; // (32,8)
    for (int i = ty; i < 32; i += 8){
        int r = rb + i, c = cb + tx;
        tile[i][tx] = (r < R && c < C) ? f2b(in[(long)r*C + c]) : (unsigned short)0;
    }
    __syncthreads();
    for (int i = ty; i < 32; i += 8){
        int c = cb + i, r = rb + tx;
        if (c < C && r < OS) out[(long)c*OS + r] = (r < R) ? tile[tx][i] : (unsigned short)0;
    }
}

// ---------------- 128x128 MFMA GEMM (m97 structure), bf16 out ----------------
__global__ __launch_bounds__(256) void gemm128(
    const unsigned short* __restrict__ A,
    const unsigned short* __restrict__ BT,
    unsigned short* __restrict__ C,
    int M, int K, int Cstride)
{
    __shared__ __align__(16) unsigned short As[128*32];
    __shared__ __align__(16) unsigned short Bs[128*32];
    const int m0 = blockIdx.y*128, n0 = blockIdx.x*128;
    const int t = threadIdx.x;
    const int wave = t >> 6, lane = t & 63;
    const int quad = lane >> 4, l16 = lane & 15;
    const int wr = wave >> 1, wc = wave & 1;

    const int srow = wave*32 + (lane >> 2);
    const int skof = (lane & 3) * 8;
    const long abase = (long)(m0 + srow)*K + skof;
    const long bbase = (long)(n0 + srow)*K + skof;
    unsigned short* asdst0 = &As[(wave*32)*32];
    unsigned short* asdst1 = &As[(wave*32+16)*32];
    unsigned short* bsdst0 = &Bs[(wave*32)*32];
    unsigned short* bsdst1 = &Bs[(wave*32+16)*32];

    f32x4 acc[4][4];
    #pragma unroll
    for (int i = 0; i < 4; i++)
        #pragma unroll
        for (int j = 0; j < 4; j++)
            #pragma unroll
            for (int r = 0; r < 4; r++) acc[i][j][r] = 0.f;

    for (int k0 = 0; k0 < K; k0 += 32){
        gl_lds16(A + abase + k0,            asdst0);
        gl_lds16(A + abase + k0 + 16L*K,    asdst1);
        gl_lds16(BT + bbase + k0,           bsdst0);
        gl_lds16(BT + bbase + k0 + 16L*K,   bsdst1);
        __syncthreads();
        bf16x8 af[4], bfr[4];
        #pragma unroll
        for (int mi = 0; mi < 4; mi++)
            af[mi] = *(const bf16x8*)(&As[(wr*64 + mi*16 + l16)*32 + quad*8]);
        #pragma unroll
        for (int ni = 0; ni < 4; ni++)
            bfr[ni] = *(const bf16x8*)(&Bs[(wc*64 + ni*16 + l16)*32 + quad*8]);
        #pragma unroll
        for (int mi = 0; mi < 4; mi++)
            #pragma unroll
            for (int ni = 0; ni < 4; ni++)
                acc[mi][ni] = __builtin_amdgcn_mfma_f32_16x16x32_bf16(
                                  af[mi], bfr[ni], acc[mi][ni], 0, 0, 0);
        __syncthreads();
    }

    #pragma unroll
    for (int mi = 0; mi < 4; mi++){
        const int rowb = m0 + wr*64 + mi*16 + quad*4;
        #pragma unroll
        for (int ni = 0; ni < 4; ni++){
            const int col = n0 + wc*64 + ni*16 + l16;
            #pragma unroll
            for (int r = 0; r < 4; r++){
                int row = rowb + r;
                if (row < M) C[(long)row*Cstride + col] = f2b(acc[mi][ni][r]);
            }
        }
    }
}

// ---------------- 64x64 MFMA GEMM: C = A[ridx?] @ BT^T (+epi) ----------------
// A: MxK bf16, BT: NnxK bf16, K % 32 == 0. epi: 0 none, 1 +bias, 2 +bias+prelu.
// obf: output bf16 (else f32). ridx: optional A row gather.
__global__ __launch_bounds__(256) void gemm_bt_ex(
    const unsigned short* __restrict__ A,
    const unsigned short* __restrict__ BT,
    void* __restrict__ Cv,
    int M, int Nn, int K, int Cstride,
    const float* __restrict__ bias,
    const float* __restrict__ alpha,
    int epi, const int* __restrict__ ridx, int obf)
{
    __shared__ __align__(16) unsigned short As[64*40];
    __shared__ __align__(16) unsigned short Bs[64*40];
    const int m0 = blockIdx.y*64, n0 = blockIdx.x*64;
    const int t = threadIdx.x;
    const int lrow = t >> 2, lk = (t & 3) * 8;
    const int wave = t >> 6, lane = t & 63;
    const int quad = lane >> 4, l16 = lane & 15;
    f32x4 acc[4];
    #pragma unroll
    for (int i = 0; i < 4; i++)
        for (int j = 0; j < 4; j++) acc[i][j] = 0.f;

    const bool arv = (m0 + lrow) < M;
    const bool brv = (n0 + lrow) < Nn;
    long arow = 0;
    if (arv) arow = ridx ? (long)ridx[m0 + lrow] : (long)(m0 + lrow);
    const long arowbase = arow * K;
    const long browbase = (long)(n0 + lrow) * K;

    for (int k0 = 0; k0 < K; k0 += 32){
        int gk = k0 + lk;
        uint4 av = {0u,0u,0u,0u};
        uint4 bv = {0u,0u,0u,0u};
        if (arv) av = *(const uint4*)(A + arowbase + gk);
        if (brv) bv = *(const uint4*)(BT + browbase + gk);
        *(uint4*)(&As[lrow*40 + lk]) = av;
        *(uint4*)(&Bs[lrow*40 + lk]) = bv;
        __syncthreads();
        bf16x8 af = *(const bf16x8*)(&As[(wave*16 + l16)*40 + quad*8]);
        #pragma unroll
        for (int nt = 0; nt < 4; nt++){
            bf16x8 bfr = *(const bf16x8*)(&Bs[(nt*16 + l16)*40 + quad*8]);
            acc[nt] = __builtin_amdgcn_mfma_f32_16x16x32_bf16(af, bfr, acc[nt], 0, 0, 0);
        }
        __syncthreads();
    }

    const int rowb = m0 + wave*16 + quad*4;
    float aval = (epi == 2) ? alpha[0] : 0.f;
    #pragma unroll
    for (int nt = 0; nt < 4; nt++){
        int col = n0 + nt*16 + l16;
        if (col >= Nn) continue;
        float bvv = epi ? bias[col] : 0.f;
        #pragma unroll
        for (int r = 0; r < 4; r++){
            int row = rowb + r;
            if (row < M){
                float v = acc[nt][r] + bvv;
                if (epi == 2 && v < 0.f) v *= aval;
                if (obf) ((unsigned short*)Cv)[(long)row*Cstride + col] = f2b(v);
                else     ((float*)Cv)[(long)row*Cstride + col] = v;
            }
        }
    }
}

// ---------------- fused GCN layer-1 aggregation (pos + neg), bf16 I/O ----------------

__global__ __launch_bounds__(256) void agg1_k(const unsigned short* __restrict__ XW,
    const float* __restrict__ ptW, const float* __restrict__ ntW,
    const int* __restrict__ flag, const int* __restrict__ negsrc,
    const float* __restrict__ dinv, const int* __restrict__ rowptr,
    const int* __restrict__ degi, const int* __restrict__ adj,
    const float* __restrict__ sb1, const float* __restrict__ sav,
    const float* __restrict__ tb1, const float* __restrict__ tav,
    unsigned short* __restrict__ H1p, unsigned short* __restrict__ H1n)
{
    int i = blockIdx.x; int t = threadIdx.x;
    int c = 2*t;                       // cols c, c+1 in [0,512)
    float di = dinv[i];
    int rs = rowptr[i], re = rs + degi[i];
    float p0 = ptW[c], p1 = ptW[c+1];
    float n0v = ntW[c], n1v = ntW[c+1];
    int fi = flag[i];
    int nsi = negsrc[i]; if (nsi < 0) nsi = 0;
    float ffi = fi ? 1.f : 0.f;
    float2 xp = bpair(*(const unsigned int*)(XW + (long)i*1024 + c));
    float2 xn = bpair(*(const unsigned int*)(XW + (long)nsi*1024 + 512 + c));
    float pa0 = (xp.x + ffi*p0) * di;
    float pa1 = (xp.y + ffi*p1) * di;
    float na0 = (fi ? n0v : xn.x) * di;
    float na1 = (fi ? n1v : xn.y) * di;
    for (int e = rs; e < re; ++e){
        int s = adj[e]; float ds = dinv[s];
        int fs = flag[s];
        int ns = negsrc[s]; if (ns < 0) ns = 0;
        float ffs = fs ? 1.f : 0.f;
        float2 sp = bpair(*(const unsigned int*)(XW + (long)s*1024 + c));
        float2 sn = bpair(*(const unsigned int*)(XW + (long)ns*1024 + 512 + c));
        pa0 += (sp.x + ffs*p0) * ds;
        pa1 += (sp.y + ffs*p1) * ds;
        na0 += (fs ? n0v : sn.x) * ds;
        na1 += (fs ? n1v : sn.y) * ds;
    }
    float sa_ = sav[0], ta_ = tav[0];
    float v0 = di*pa0 + sb1[c];   if (v0 < 0.f) v0 *= sa_;
    float v1 = di*pa1 + sb1[c+1]; if (v1 < 0.f) v1 *= sa_;
    float w0 = di*na0 + tb1[c];   if (w0 < 0.f) w0 *= ta_;
    float w1 = di*na1 + tb1[c+1]; if (w1 < 0.f) w1 *= ta_;
    *(unsigned int*)(H1p + (long)i*512 + c) = packb(v0, v1);
    *(unsigned int*)(H1n + (long)i*512 + c) = packb(w0, w1);
}

__global__ __launch_bounds__(128) void agg128_k(const unsigned short* __restrict__ In,
    const float* __restrict__ dinv, const int* __restrict__ rowptr,
    const int* __restrict__ degi, const int* __restrict__ adj,
    const float* __restrict__ b2, const float* __restrict__ a2,
    unsigned short* __restrict__ Out)
{
    int i = blockIdx.x, t = threadIdx.x;
    float di = dinv[i];
    int rs = rowptr[i], re = rs + degi[i];
    float acc = b2f(In[(long)i*128 + t]) * di;
    for (int e = rs; e < re; ++e){
        int s = adj[e];
        acc += b2f(In[(long)s*128 + t]) * dinv[s];
    }
    float v = di*acc + b2[t];
    float a = a2[0]; if (v < 0.f) v *= a;
    Out[(long)i*128 + t] = f2b(v);
}

__global__ __launch_bounds__(128) void aggrec_k(const unsigned short* __restrict__ recPre,
    const float* __restrict__ dinv, const int* __restrict__ rowptr,
    const int* __restrict__ degi, const int* __restrict__ adj,
    const int* __restrict__ flag, const int* __restrict__ perm,
    unsigned short* __restrict__ recAgg)
{
    int b = blockIdx.x, t = threadIdx.x;
    int i = perm[b];
    float di = dinv[i];
    int rs = rowptr[i], re = rs + degi[i];
    float acc = 0.f; // self loop: i is a mask node -> rec row zeroed
    for (int e = rs; e < re; ++e){
        int s = adj[e];
        if (!flag[s]) acc += b2f(recPre[(long)s*128 + t]) * dinv[s];
    }
    recAgg[(long)b*128 + t] = f2b(di * acc);
}

// ---------------- DGI head ----------------

__global__ __launch_bounds__(128) void meanp_k(const float* __restrict__ posZ,
                                               float* svecraw){
    int j = threadIdx.x;
    int r0 = blockIdx.x*64, r1 = r0 + 64; if (r1 > NM) r1 = NM;
    float s = 0.f;
    for (int r = r0; r < r1; ++r) s += posZ[(long)r*128 + j];
    atomicAdd(&svecraw[j], s);
}

__global__ void ws_k(const float* __restrict__ dgiW, const float* __restrict__ svecraw,
                     float* wsv){
    __shared__ float s[128];
    int i = threadIdx.x; // 128
    s[i] = 1.f/(1.f + expf(-svecraw[i]/(float)NM));
    __syncthreads();
    float a = 0.f;
    for (int j = 0; j < 128; ++j) a += dgiW[i*128 + j] * s[j];
    wsv[i] = a;
}

__global__ __launch_bounds__(256) void dgi_k(const float* __restrict__ posZ,
    const float* __restrict__ negZ, const float* __restrict__ wsv, float* scal){
    int row = blockIdx.x*4 + (threadIdx.x >> 6);
    int lane = threadIdx.x & 63;
    if (row >= 2*NM) return;
    const float* Z = (row < NM) ? posZ : negZ;
    int r = (row < NM) ? row : row - NM;
    float v = Z[(long)r*128 + lane] * wsv[lane]
            + Z[(long)r*128 + 64 + lane] * wsv[64 + lane];
    for (int off = 32; off; off >>= 1) v += __shfl_down(v, off, 64);
    if (lane == 0){
        float d = 1.f/(1.f + expf(-v));
        float lg = (row < NM) ? logf(d + 1e-15f) : logf(1.f - d + 1e-15f);
        atomicAdd(&scal[(row < NM) ? 0 : 1], lg);
    }
}

// ---------------- cosine feature loss ----------------

__global__ __launch_bounds__(256) void cos_k(const float* __restrict__ x,
    const unsigned short* __restrict__ recMask, const int* __restrict__ perm,
    float* scal){
    int b = blockIdx.x, t = threadIdx.x;
    long xi = (long)perm[b]*DD;
    long ri = (long)b*DD;
    float dot = 0.f, nx = 0.f, nr = 0.f;
    for (int d = t; d < DD; d += 256){
        float xv = x[xi + d], rv = b2f(recMask[ri + d]);
        dot += xv*rv; nx += xv*xv; nr += rv*rv;
    }
    for (int off = 32; off; off >>= 1){
        dot += __shfl_down(dot, off, 64);
        nx  += __shfl_down(nx,  off, 64);
        nr  += __shfl_down(nr,  off, 64);
    }
    __shared__ float sd[4], sx[4], sr[4];
    int w = t >> 6, lane = t & 63;
    if (lane == 0){ sd[w] = dot; sx[w] = nx; sr[w] = nr; }
    __syncthreads();
    if (t == 0){
        float Dv = sd[0]+sd[1]+sd[2]+sd[3];
        float Xv = sx[0]+sx[1]+sx[2]+sx[3];
        float Rv = sr[0]+sr[1]+sr[2]+sr[3];
        float c = Dv/(fmaxf(sqrtf(Xv),1e-12f)*fmaxf(sqrtf(Rv),1e-12f));
        float e = 1.f - c;
        atomicAdd(&scal[2], e*e);
    }
}

__global__ void fin_k(const float* __restrict__ scal, float* out){
    float feat = scal[2]/(float)NM;
    float dgi  = -(scal[0]/(float)NM) - (scal[1]/(float)NM);
    out[0] = feat;
    out[1] = dgi;
}

// ---------------- launch ----------------

extern "C" void kernel_launch(void* const* d_in, const int* in_sizes, int n_in,
                              void* d_out, int out_size, void* d_ws, size_t ws_size,
                              hipStream_t stream) {
    (void)in_sizes; (void)n_in; (void)out_size; (void)d_ws; (void)ws_size;
    const float* x  = (const float*)d_in[0];
    const int* ei   = (const int*)d_in[1];
    const int* perm = (const int*)d_in[2];
    const int* shuf = (const int*)d_in[3];
    const float* sW1 = (const float*)d_in[4];
    const float* sb1 = (const float*)d_in[5];
    const float* sa  = (const float*)d_in[6];
    const float* sW2 = (const float*)d_in[7];
    const float* sb2 = (const float*)d_in[8];
    const float* tW1 = (const float*)d_in[9];
    const float* tb1 = (const float*)d_in[10];
    const float* ta  = (const float*)d_in[11];
    const float* tW2 = (const float*)d_in[12];
    const float* tb2 = (const float*)d_in[13];
    const float* pW1 = (const float*)d_in[14];
    const float* pb1 = (const float*)d_in[15];
    const float* pa  = (const float*)d_in[16];
    const float* pW2 = (const float*)d_in[17];
    const float* pb2 = (const float*)d_in[18];
    const float* tpW1 = (const float*)d_in[19];
    const float* tpb1 = (const float*)d_in[20];
    const float* tpa  = (const float*)d_in[21];
    const float* tpW2 = (const float*)d_in[22];
    const float* tpb2 = (const float*)d_in[23];
    const float* dgiW = (const float*)d_in[24];
    const float* posT = (const float*)d_in[25];
    const float* negT = (const float*)d_in[26];
    const float* e2dW = (const float*)d_in[27];
    const float* dW   = (const float*)d_in[28];
    const float* db   = (const float*)d_in[29];
    float* out = (float*)d_out;

    void* wsp = nullptr;
    hipGetSymbolAddress(&wsp, HIP_SYMBOL(g_ws));
    char* base = (char*)wsp;
    size_t off = 0;
    auto alloc = [&](size_t b){ size_t o = off; off = (off + b + 255) & ~(size_t)255; return o; };

    float* dinv    = (float*)(base + alloc(NND*4));
    int* degi      = (int*)  (base + alloc(NND*4));
    int* rowptr    = (int*)  (base + alloc(NND*4));
    int* cursor    = (int*)  (base + alloc(NND*4));
    int* adj       = (int*)  (base + alloc(EE*4));
    int* flag      = (int*)  (base + alloc(NND*4));
    int* negsrc    = (int*)  (base + alloc(NND*4));
    int* ecnt      = (int*)  (base + alloc(16*4));
    float* ptW     = (float*)(base + alloc(HH*4));
    float* ntW     = (float*)(base + alloc(HH*4));
    float* svecraw = (float*)(base + alloc(128*4));
    float* wsv     = (float*)(base + alloc(128*4));
    float* scal    = (float*)(base + alloc(16*4));

    unsigned short* xb    = (unsigned short*)(base + alloc((size_t)MP*KP*2));
    unsigned short* W1T   = (unsigned short*)(base + alloc((size_t)NW*KP*2));
    unsigned short* sW2T  = (unsigned short*)(base + alloc((size_t)LL*HH*2));
    unsigned short* tW2T  = (unsigned short*)(base + alloc((size_t)LL*HH*2));
    unsigned short* pW1T  = (unsigned short*)(base + alloc((size_t)PP*LL*2));
    unsigned short* pW2T  = (unsigned short*)(base + alloc((size_t)LL*PP*2));
    unsigned short* tpW1T = (unsigned short*)(base + alloc((size_t)PP*LL*2));
    unsigned short* tpW2T = (unsigned short*)(base + alloc((size_t)LL*PP*2));
    unsigned short* e2dWT = (unsigned short*)(base + alloc((size_t)LL*LL*2));
    unsigned short* dWT   = (unsigned short*)(base + alloc((size_t)DD*LL*2));

    unsigned short* XW      = (unsigned short*)(base + alloc((size_t)NND*1024*2));
    unsigned short* H1p     = (unsigned short*)(base + alloc((size_t)NND*512*2));
    unsigned short* H1n     = (unsigned short*)(base + alloc((size_t)NND*512*2));
    unsigned short* M2p     = (unsigned short*)(base + alloc((size_t)NND*128*2));
    unsigned short* M2n     = (unsigned short*)(base + alloc((size_t)NND*128*2));
    unsigned short* repP    = (unsigned short*)(base + alloc((size_t)NND*128*2));
    unsigned short* repN    = (unsigned short*)(base + alloc((size_t)NND*128*2));
    unsigned short* posH    = (unsigned short*)(base + alloc((size_t)NM*256*2));
    unsigned short* negH    = (unsigned short*)(base + alloc((size_t)NM*256*2));
    float* posZ             = (float*)(base + alloc((size_t)NM*128*4));
    float* negZ             = (float*)(base + alloc((size_t)NM*128*4));
    unsigned short* recPre  = (unsigned short*)(base + alloc((size_t)NND*128*2));
    unsigned short* recAgg  = (unsigned short*)(base + alloc((size_t)NM*128*2));
    unsigned short* recMask = (unsigned short*)(base + alloc((size_t)NM*DD*2));

    // ---- graph build (scan-free) ----
    init_k<<<(NND+255)/256, 256, 0, stream>>>(degi, cursor, scal, ptW, ntW, svecraw, ecnt);
    flag_k<<<(NND+255)/256, 256, 0, stream>>>(perm, shuf, flag, negsrc);
    count_k<<<(EE+255)/256, 256, 0, stream>>>(ei, degi);
    alloc_k<<<(NND+255)/256, 256, 0, stream>>>(degi, dinv, rowptr, ecnt);
    fill_k<<<(EE+255)/256, 256, 0, stream>>>(ei, rowptr, cursor, adj);
    tok_k<<<dim3(2,8), 512, 0, stream>>>(posT, negT, sW1, tW1, ptW, ntW);

    // ---- bf16 staging ----
    cast_pad_x_k<<<(int)(((long)MP*(KP/8) + 255)/256), 256, 0, stream>>>(x, xb);
    {
        TBatch tb;
        const float* ins[10] = {sW1, tW1, sW2, tW2, pW1, pW2, tpW1, tpW2, e2dW, dW};
        unsigned short* outs[10] = {W1T, W1T + (size_t)HH*KP, sW2T, tW2T, pW1T, pW2T,
                                    tpW1T, tpW2T, e2dWT, dWT};
        int Rs[10]  = {DD, DD, HH, HH, LL, PP, LL, PP, LL, LL};
        int Cs[10]  = {HH, HH, LL, LL, PP, LL, PP, LL, LL, DD};
        int OSs[10] = {KP, KP, HH, HH, LL, PP, LL, PP, LL, LL};
        int cum = 0;
        for (int d = 0; d < 10; d++){
            tb.in[d] = ins[d]; tb.out[d] = outs[d];
            tb.R[d] = Rs[d]; tb.C[d] = Cs[d]; tb.OS[d] = OSs[d];
            tb.t0[d] = cum;
            cum += (OSs[d]/32) * ((Cs[d] + 31)/32);
        }
        tb.t0[10] = cum;
        transbatch_k<<<cum, dim3(32,8), 0, stream>>>(tb);
    }

    // ---- encoder layer 1 (MFMA 128x128, bf16 out) + fused aggregation ----
    gemm128<<<dim3(NW/128, MP/128), 256, 0, stream>>>(xb, W1T, XW, NND, KP, 1024);
    agg1_k<<<NND, 256, 0, stream>>>(XW, ptW, ntW, flag, negsrc, dinv, rowptr, degi, adj,
                                    sb1, sa, tb1, ta, H1p, H1n);

    // ---- encoder layer 2 (MFMA) ----
    gemm_bt_ex<<<dim3(2,157), 256, 0, stream>>>(H1p, sW2T, M2p, NND, LL, HH, LL,
                                                nullptr, nullptr, 0, nullptr, 1);
    gemm_bt_ex<<<dim3(2,157), 256, 0, stream>>>(H1n, tW2T, M2n, NND, LL, HH, LL,
                                                nullptr, nullptr, 0, nullptr, 1);
    agg128_k<<<NND, 128, 0, stream>>>(M2p, dinv, rowptr, degi, adj, sb2, sa, repP);
    agg128_k<<<NND, 128, 0, stream>>>(M2n, dinv, rowptr, degi, adj, tb2, ta, repN);

    // ---- projections on mask rows (MFMA, gathered A via perm) ----
    gemm_bt_ex<<<dim3(4,47), 256, 0, stream>>>(repP, pW1T, posH, NM, PP, LL, PP,
                                               pb1, pa, 2, perm, 1);
    gemm_bt_ex<<<dim3(2,47), 256, 0, stream>>>(posH, pW2T, posZ, NM, LL, PP, LL,
                                               pb2, nullptr, 1, nullptr, 0);
    gemm_bt_ex<<<dim3(4,47), 256, 0, stream>>>(repN, tpW1T, negH, NM, PP, LL, PP,
                                               tpb1, tpa, 2, perm, 1);
    gemm_bt_ex<<<dim3(2,47), 256, 0, stream>>>(negH, tpW2T, negZ, NM, LL, PP, LL,
                                               tpb2, nullptr, 1, nullptr, 0);

    // ---- DGI loss ----
    meanp_k<<<47, 128, 0, stream>>>(posZ, svecraw);
    ws_k<<<1, 128, 0, stream>>>(dgiW, svecraw, wsv);
    dgi_k<<<(2*NM)/4, 256, 0, stream>>>(posZ, negZ, wsv, scal);

    // ---- decoder + feature loss (MFMA) ----
    gemm_bt_ex<<<dim3(2,157), 256, 0, stream>>>(repP, e2dWT, recPre, NND, LL, LL, LL,
                                                nullptr, nullptr, 0, nullptr, 1);
    aggrec_k<<<NM, 128, 0, stream>>>(recPre, dinv, rowptr, degi, adj, flag, perm, recAgg);
    gemm_bt_ex<<<dim3(47,47), 256, 0, stream>>>(recAgg, dWT, recMask, NM, DD, LL, DD,
                                                db, nullptr, 1, nullptr, 1);
    cos_k<<<NM, 256, 0, stream>>>(x, recMask, perm, scal);

    fin_k<<<1, 1, 0, stream>>>(scal, out);
}